// Round 11
// baseline (2961.280 us; speedup 1.0000x reference)
//
#include <hip/hip_runtime.h>
#include <hip/hip_bf16.h>
#include <math.h>

#define BATCH   8
#define NBINS   512
#define BINSZ   10
#define DMODEL  1024
#define NHEAD   8
#define DHEAD   128
#define NLAYER  4
#define NEXP    30
#define TOPK    4
#define SEQ     513            // NBINS + 1
#define NTOK    (BATCH*SEQ)    // 4104
#define NBINTOT (BATCH*NBINS)  // 4096
#define CAPACITY 1152
#define TKF     (NTOK*TOPK)    // 16416
#define QKVLD   3072           // packed qkv row stride

typedef __attribute__((ext_vector_type(8))) __bf16 bf16x8;
typedef __attribute__((ext_vector_type(4))) __bf16 bf16x4;
typedef __attribute__((ext_vector_type(4))) float f32x4;

__device__ __forceinline__ float gelu_f(float x) {
  return 0.5f * x * (1.0f + erff(x * 0.7071067811865475f));
}

__device__ __forceinline__ bf16x8 bf8_zero() {
  int4 z = make_int4(0, 0, 0, 0);
  return __builtin_bit_cast(bf16x8, z);
}

// async global->LDS, 16B per lane; LDS dest must be wave-uniform base + lane*16.
__device__ __forceinline__ void gload16(const __bf16* g, __bf16* l) {
  __builtin_amdgcn_global_load_lds((const __attribute__((address_space(1))) void*)g,
                                   (__attribute__((address_space(3))) void*)l, 16, 0, 0);
}

// ---------------------------------------------------------------- weight convert + transpose
__global__ __launch_bounds__(256) void transpose_w(const float* __restrict__ src,
                                                   __bf16* __restrict__ dst, size_t mstride) {
  int mat = blockIdx.y;
  int tile = blockIdx.x;          // 0..255
  int kt = (tile >> 4) * 64;
  int nt = (tile & 15) * 64;
  const float* s = src + (size_t)mat * 1024 * 1024;
  __bf16* d = dst + (size_t)mat * mstride;
  __shared__ float t[64][65];
  int tid = threadIdx.x;
  int r = tid >> 4, c4 = (tid & 15) * 4;
#pragma unroll
  for (int i = 0; i < 4; i++) {
    float4 v = *(const float4*)(s + (size_t)(kt + r + i*16) * 1024 + nt + c4);
    t[r + i*16][c4+0] = v.x; t[r + i*16][c4+1] = v.y;
    t[r + i*16][c4+2] = v.z; t[r + i*16][c4+3] = v.w;
  }
  __syncthreads();
  int r2 = tid >> 2, c2 = (tid & 3) * 16;
  bf16x8 o0, o1;
#pragma unroll
  for (int j = 0; j < 8; j++) { o0[j] = (__bf16)t[c2+j][r2]; o1[j] = (__bf16)t[c2+8+j][r2]; }
  *(bf16x8*)(d + (size_t)(nt + r2) * 1024 + kt + c2)     = o0;
  *(bf16x8*)(d + (size_t)(nt + r2) * 1024 + kt + c2 + 8) = o1;
}

// ---------------------------------------------------------------- conv frontend (named-scalar accs)
#define CSTEP(acc, T, DIL, hr, wA, wB, wC) { \
  float vv_ = (wB) * (hr)[T]; \
  if ((T) >= (DIL)) vv_ = fmaf((wA), (hr)[(T)-(DIL)], vv_); \
  if ((T) + (DIL) <= 9) vv_ = fmaf((wC), (hr)[(T)+(DIL)], vv_); \
  acc += vv_; }

#define CALL10(DIL, hr, wA, wB, wC) \
  CSTEP(t0,0,DIL,hr,wA,wB,wC); CSTEP(t1,1,DIL,hr,wA,wB,wC); \
  CSTEP(t2,2,DIL,hr,wA,wB,wC); CSTEP(t3,3,DIL,hr,wA,wB,wC); \
  CSTEP(t4,4,DIL,hr,wA,wB,wC); CSTEP(t5,5,DIL,hr,wA,wB,wC); \
  CSTEP(t6,6,DIL,hr,wA,wB,wC); CSTEP(t7,7,DIL,hr,wA,wB,wC); \
  CSTEP(t8,8,DIL,hr,wA,wB,wC); CSTEP(t9,9,DIL,hr,wA,wB,wC);

#define ZERO10 float t0=0.f,t1=0.f,t2=0.f,t3=0.f,t4=0.f,t5=0.f,t6=0.f,t7=0.f,t8=0.f,t9=0.f;

#define STORE10(dst, sc, sh) \
  (dst)[0]=gelu_f(t0*(sc)+(sh)); (dst)[1]=gelu_f(t1*(sc)+(sh)); \
  (dst)[2]=gelu_f(t2*(sc)+(sh)); (dst)[3]=gelu_f(t3*(sc)+(sh)); \
  (dst)[4]=gelu_f(t4*(sc)+(sh)); (dst)[5]=gelu_f(t5*(sc)+(sh)); \
  (dst)[6]=gelu_f(t6*(sc)+(sh)); (dst)[7]=gelu_f(t7*(sc)+(sh)); \
  (dst)[8]=gelu_f(t8*(sc)+(sh)); (dst)[9]=gelu_f(t9*(sc)+(sh));

__global__ __launch_bounds__(64) void conv_frontend(const float* __restrict__ x,
                              const float* __restrict__ w1, const float* __restrict__ w2,
                              const float* __restrict__ w3,
                              const float* __restrict__ g1, const float* __restrict__ b1,
                              const float* __restrict__ g2, const float* __restrict__ b2,
                              const float* __restrict__ g3, const float* __restrict__ b3,
                              float* __restrict__ feat, int* __restrict__ msk) {
  const float bnscale = 0.9999950000374997f;   // 1/sqrt(1+1e-5)
  int bin = blockIdx.x;
  int c = threadIdx.x;
  __shared__ float xs[BINSZ];
  __shared__ float h1[16][BINSZ];
  __shared__ float h2[32][BINSZ];
  if (c < BINSZ) xs[c] = x[bin*BINSZ + c];
  if (c == 0) {
    int all = 1;
    for (int t = 0; t < BINSZ; t++) if (x[bin*BINSZ+t] != -100.0f) { all = 0; break; }
    msk[bin] = all;
  }
  __syncthreads();
  if (c < 16) {
    float sc = g1[c]*bnscale, sh = b1[c];
    float wA = w1[c*3], wB = w1[c*3+1], wC = w1[c*3+2];
    const float* hr = &xs[0];
    ZERO10;
    CALL10(1, hr, wA, wB, wC);
    STORE10(&h1[c][0], sc, sh);
  }
  __syncthreads();
  if (c < 32) {
    float sc = g2[c]*bnscale, sh = b2[c];
    ZERO10;
    for (int ci = 0; ci < 16; ci++) {
      const float* w = w2 + (c*16+ci)*3;
      float wA = w[0], wB = w[1], wC = w[2];
      const float* hr = &h1[ci][0];
      CALL10(2, hr, wA, wB, wC);
    }
    STORE10(&h2[c][0], sc, sh);
  }
  __syncthreads();
  {
    float sc = g3[c]*bnscale, sh = b3[c];
    ZERO10;
    for (int ci = 0; ci < 32; ci++) {
      const float* w = w3 + (c*32+ci)*3;
      float wA = w[0], wB = w[1], wC = w[2];
      const float* hr = &h2[ci][0];
      CALL10(4, hr, wA, wB, wC);
    }
    float mean = gelu_f(t0*sc+sh) + gelu_f(t1*sc+sh) + gelu_f(t2*sc+sh)
               + gelu_f(t3*sc+sh) + gelu_f(t4*sc+sh) + gelu_f(t5*sc+sh)
               + gelu_f(t6*sc+sh) + gelu_f(t7*sc+sh) + gelu_f(t8*sc+sh)
               + gelu_f(t9*sc+sh);
    feat[bin*64 + c] = mean * 0.1f;
  }
}

// ---------------------------------------------------------------- embed + PE
__global__ void embed_kernel(const float* __restrict__ feat, const int* __restrict__ msk,
                             const float* __restrict__ proj_w, const float* __restrict__ proj_b,
                             const float* __restrict__ cls_token, const float* __restrict__ mask_token,
                             float* __restrict__ h) {
  int s_ = blockIdx.x;
  int b  = blockIdx.y;
  int tid = threadIdx.x;
  __shared__ __align__(16) float fs[64];
  float out[4];
  if (s_ == 0) {
#pragma unroll
    for (int u = 0; u < 4; u++) out[u] = cls_token[tid*4+u];
  } else {
    int bin = b*NBINS + (s_-1);
    if (tid < 16) ((float4*)fs)[tid] = ((const float4*)(feat + (size_t)bin*64))[tid];
    __syncthreads();
    int m_ = msk[bin];
#pragma unroll
    for (int u = 0; u < 4; u++) {
      int d = tid*4+u;
      float acc = proj_b[d];
      for (int ci = 0; ci < 64; ci++) acc = fmaf(fs[ci], proj_w[ci*DMODEL + d], acc);
      out[u] = m_ ? mask_token[d] : acc;
    }
  }
  const float c0 = -0.008994473019507992f;  // -ln(10000)/1024
#pragma unroll
  for (int u = 0; u < 4; u++) {
    int d = tid*4+u;
    float div = expf(c0 * (float)(d & ~1));
    float ang = (float)s_ * div;
    float pe = (d & 1) ? cosf(ang) : sinf(ang);
    h[((size_t)(b*SEQ + s_))*DMODEL + d] = out[u] + pe;
  }
}

// ---------------------------------------------------------------- layernorm (fp32 out + bf16 out)
__global__ void ln_kernel(const float* __restrict__ x, float* __restrict__ out,
                          __bf16* __restrict__ outb,
                          const float* __restrict__ g, const float* __restrict__ b) {
  int t = blockIdx.x, tid = threadIdx.x;
  float4 v = ((const float4*)(x + (size_t)t*DMODEL))[tid];
  float s  = v.x+v.y+v.z+v.w;
  float sq = v.x*v.x+v.y*v.y+v.z*v.z+v.w*v.w;
  for (int off = 32; off; off >>= 1) { s += __shfl_down(s, off); sq += __shfl_down(sq, off); }
  __shared__ float ss[4], ssq[4], mv[2];
  int w = tid >> 6, l = tid & 63;
  if (l == 0) { ss[w] = s; ssq[w] = sq; }
  __syncthreads();
  if (tid == 0) {
    float a = 0, c = 0;
    for (int i = 0; i < 4; i++) { a += ss[i]; c += ssq[i]; }
    float mean = a * (1.f/DMODEL);
    float var  = c * (1.f/DMODEL) - mean*mean;
    mv[0] = mean; mv[1] = rsqrtf(var + 1e-5f);
  }
  __syncthreads();
  float mean = mv[0], inv = mv[1];
  float4 gg = ((const float4*)g)[tid];
  float4 bb = ((const float4*)b)[tid];
  float4 o;
  o.x = (v.x-mean)*inv*gg.x + bb.x;
  o.y = (v.y-mean)*inv*gg.y + bb.y;
  o.z = (v.z-mean)*inv*gg.z + bb.z;
  o.w = (v.w-mean)*inv*gg.w + bb.w;
  ((float4*)(out + (size_t)t*DMODEL))[tid] = o;
  bf16x4 ob;
  ob[0] = (__bf16)o.x; ob[1] = (__bf16)o.y; ob[2] = (__bf16)o.z; ob[3] = (__bf16)o.w;
  *(bf16x4*)(outb + (size_t)t*DMODEL + tid*4) = ob;
}

// ---------------------------------------------------------------- bf16 MFMA GEMM, 128x128 tile
// GLD=0: reg-prefetch staging (R9-proven; best at small grids).
// GLD=1: global_load_lds width-16 staging (m97 structure; needs >=3 blocks/CU — MoE only).
// MODE 0: fused QKV — Wt [3072][1024], C bf16 row-stride 3072, bias per 1024-window
// MODE 1: WO residual — C f32 +=
// MODE 2: MoE ffn1 — gather f>>2, gelu -> hid bf16
// MODE 3: MoE ffn2 — gather f, gate -> yb f32
template<int MODE, int GLD>
__global__ __launch_bounds__(512) void gemm_bf16(
    const __bf16* __restrict__ A, const __bf16* __restrict__ Wt,
    const float* __restrict__ b0, const float* __restrict__ b1, const float* __restrict__ b2,
    void* __restrict__ C, int M,
    const int* __restrict__ rowmap, const int* __restrict__ cnt,
    const float* __restrict__ gate) {
  int tid = threadIdx.x;
  int rowbase, validrows, e = 0;
  const __bf16* Wb = Wt;
  if (MODE <= 1) {
    rowbase = blockIdx.x * 128;
    validrows = M - rowbase; if (validrows > 128) validrows = 128;
  } else {
    e = blockIdx.x / 9;
    int p0 = (blockIdx.x % 9) * 128;
    int ce = cnt[e];
    if (p0 >= ce) return;
    rowbase = p0;
    validrows = ce - p0; if (validrows > 128) validrows = 128;
    Wb = Wt + (size_t)e * 1024 * 1024;
  }
  int colbase = blockIdx.y * 128;

  __shared__ __align__(16) __bf16 As[4][128][8];   // [kgroup][row][8k]  (8 KB)
  __shared__ __align__(16) __bf16 Bs[4][128][8];   // [kgroup][col][8k]  (8 KB)
  __shared__ int srcrow[128];
  __shared__ int frow[128];

  if (tid < 128) {
    if (MODE <= 1) { srcrow[tid] = rowbase + tid; frow[tid] = rowbase + tid; }
    else if (tid < validrows) {
      int f = rowmap[e*CAPACITY + rowbase + tid];
      frow[tid] = f;
      srcrow[tid] = (MODE == 2) ? (f >> 2) : f;
    } else { frow[tid] = 0; srcrow[tid] = 0; }
  }
  __syncthreads();

  int w  = tid >> 6;
  int wr = w & 3, wc = w >> 2;        // wave quadrant: rows wr*32.., cols wc*64..
  int l  = tid & 63;
  int lr = l & 15, lg = l >> 4;

  f32x4 acc[2][4] = {};

  if (GLD == 0) {
    // ---- register-prefetch staging (R9)
    int arow = tid >> 2, ag = tid & 3;
    int wcol = tid & 127, wgp = tid >> 7;
    bool aval = (arow < validrows);
    const __bf16* Ap = A + (size_t)srcrow[arow] * 1024 + ag * 8;
    const __bf16* Wp = Wb + (size_t)(colbase + wcol) * 1024 + wgp * 8;

    bf16x8 areg = bf8_zero(), breg;
    if (aval) areg = *(const bf16x8*)(Ap);
    breg = *(const bf16x8*)(Wp);

    for (int kt = 0; kt < 1024; kt += 32) {
      __syncthreads();
      *(bf16x8*)&As[ag][arow][0] = areg;
      *(bf16x8*)&Bs[wgp][wcol][0] = breg;
      __syncthreads();

      if (kt + 32 < 1024) {
        if (aval) areg = *(const bf16x8*)(Ap + kt + 32);
        breg = *(const bf16x8*)(Wp + kt + 32);
      }

      bf16x8 af[2], bfr[4];
      af[0] = *(const bf16x8*)&As[lg][wr*32 + lr][0];
      af[1] = *(const bf16x8*)&As[lg][wr*32 + 16 + lr][0];
#pragma unroll
      for (int fj = 0; fj < 4; fj++) bfr[fj] = *(const bf16x8*)&Bs[lg][wc*64 + fj*16 + lr][0];
#pragma unroll
      for (int fi = 0; fi < 2; fi++)
#pragma unroll
        for (int fj = 0; fj < 4; fj++)
          acc[fi][fj] = __builtin_amdgcn_mfma_f32_16x16x32_bf16(af[fi], bfr[fj], acc[fi][fj], 0, 0, 0);
    }
  } else {
    // ---- global_load_lds staging (m97 structure): LDS dest = tid*16B linear.
    // As flat elem (ag*128+arow)*8 == tid*8 when ag=tid>>7, arow=tid&127 (same for Bs).
    int arow2 = tid & 127, ag2 = tid >> 7;
    const __bf16* ApG = A + (size_t)srcrow[arow2] * 1024 + ag2 * 8;
    const __bf16* BpG = Wb + (size_t)(colbase + arow2) * 1024 + ag2 * 8;
    __bf16* AsL = &As[0][0][0] + tid * 8;
    __bf16* BsL = &Bs[0][0][0] + tid * 8;

    for (int kt = 0; kt < 1024; kt += 32) {
      gload16(ApG + kt, AsL);
      gload16(BpG + kt, BsL);
      __syncthreads();

      bf16x8 af[2], bfr[4];
      af[0] = *(const bf16x8*)&As[lg][wr*32 + lr][0];
      af[1] = *(const bf16x8*)&As[lg][wr*32 + 16 + lr][0];
#pragma unroll
      for (int fj = 0; fj < 4; fj++) bfr[fj] = *(const bf16x8*)&Bs[lg][wc*64 + fj*16 + lr][0];
#pragma unroll
      for (int fi = 0; fi < 2; fi++)
#pragma unroll
        for (int fj = 0; fj < 4; fj++)
          acc[fi][fj] = __builtin_amdgcn_mfma_f32_16x16x32_bf16(af[fi], bfr[fj], acc[fi][fj], 0, 0, 0);
      __syncthreads();
    }
  }

  // epilogue: C/D layout col = l&15, row = (l>>4)*4 + i
  if (MODE == 0) {
    int which = colbase >> 10;              // block-uniform
    int colb0 = colbase & 1023;
    const float* bsel = (which == 0) ? b0 : (which == 1) ? b1 : b2;
#pragma unroll
    for (int fj = 0; fj < 4; fj++) {
      int col = wc*64 + fj*16 + lr;
      float bvv = bsel[colb0 + col];
#pragma unroll
      for (int fi = 0; fi < 2; fi++)
#pragma unroll
        for (int i = 0; i < 4; i++) {
          int r = wr*32 + fi*16 + lg*4 + i;
          if (r >= validrows) continue;
          ((__bf16*)C)[(size_t)(rowbase + r)*QKVLD + colbase + col] = (__bf16)(acc[fi][fj][i] + bvv);
        }
    }
  } else {
    const float* bptr = (MODE >= 2) ? (b0 + (size_t)e * 1024) : b0;
#pragma unroll
    for (int fj = 0; fj < 4; fj++) {
      int col = wc*64 + fj*16 + lr;
      float bvv = bptr[colbase + col];
#pragma unroll
      for (int fi = 0; fi < 2; fi++)
#pragma unroll
        for (int i = 0; i < 4; i++) {
          int r = wr*32 + fi*16 + lg*4 + i;
          if (r >= validrows) continue;
          float val = acc[fi][fj][i] + bvv;
          if (MODE == 1) {
            float* p = (float*)C + (size_t)(rowbase + r)*1024 + colbase + col;
            *p = *p + val;
          } else if (MODE == 2) {
            ((__bf16*)C)[(size_t)frow[r]*1024 + colbase + col] = (__bf16)gelu_f(val);
          } else {
            ((float*)C)[(size_t)frow[r]*1024 + colbase + col] = gate[frow[r]] * val;
          }
        }
    }
  }
}

// ---------------------------------------------------------------- MFMA flash attention (packed qkv, stride 3072)
__global__ __launch_bounds__(256) void attn_mfma(const __bf16* __restrict__ qkv,
                                                 __bf16* __restrict__ o) {
  int qt = blockIdx.x;
  int bh = blockIdx.y;
  int b = bh >> 3, hh = bh & 7;
  int tid = threadIdx.x;
  int wid = tid >> 6, l = tid & 63;
  int lr = l & 15, lg = l >> 4;

  __shared__ __align__(16) __bf16 Ks[64*128];   // [kk][d] row-major, swizzled
  __shared__ __align__(16) __bf16 Vt[128*64];   // [d][kk] row-major, swizzled

  const float scale = 0.08838834764831845f;  // 1/sqrt(128)

  int qtok = qt*64 + wid*16 + lr;
  int qtokc = qtok < SEQ ? qtok : SEQ-1;
  const __bf16* qrow = qkv + (size_t)(b*SEQ + qtokc)*QKVLD + hh*DHEAD;
  bf16x8 qf[4];
#pragma unroll
  for (int c = 0; c < 4; c++) qf[c] = *(const bf16x8*)(qrow + c*32 + lg*8);

  float mreg = -1e30f, lsum = 0.f;
  f32x4 Oacc[8] = {};

  int krow = tid & 63, kdc = tid >> 6;   // K staging: row, 32-d chunk
  int vd = tid & 127, vkg0 = tid >> 7;   // V staging: d column, kk-group base

  for (int kt = 0; kt < 9; kt++) {
    int kt0 = kt*64;
    __syncthreads();
    {
      int tok = kt0 + krow; if (tok >= SEQ) tok = SEQ-1;
      const __bf16* kr = qkv + (size_t)(b*SEQ + tok)*QKVLD + 1024 + hh*DHEAD + kdc*32;
#pragma unroll
      for (int s2 = 0; s2 < 4; s2++) {
        bf16x8 t = *(const bf16x8*)(kr + s2*8);
        int byte = (krow*256 + (kdc*32 + s2*8)*2) ^ ((krow & 7) << 4);
        *(bf16x8*)((char*)Ks + byte) = t;
      }
    }
    {
#pragma unroll
      for (int it = 0; it < 4; it++) {
        int kkg = vkg0 + it*2;
        bf16x8 t;
#pragma unroll
        for (int j = 0; j < 8; j++) {
          int tok = kt0 + kkg*8 + j; if (tok >= SEQ) tok = SEQ-1;
          t[j] = qkv[(size_t)(b*SEQ + tok)*QKVLD + 2048 + hh*DHEAD + vd];
        }
        int byte = (vd*128 + kkg*16) ^ ((vd & 7) << 4);
        *(bf16x8*)((char*)Vt + byte) = t;
      }
    }
    __syncthreads();

    f32x4 sacc[4] = {};
#pragma unroll
    for (int c = 0; c < 4; c++) {
#pragma unroll
      for (int jb = 0; jb < 4; jb++) {
        int row = jb*16 + lr;
        int byte = (row*256 + (c*32 + lg*8)*2) ^ ((lr & 7) << 4);
        bf16x8 af = *(const bf16x8*)((const char*)Ks + byte);
        sacc[jb] = __builtin_amdgcn_mfma_f32_16x16x32_bf16(af, qf[c], sacc[jb], 0, 0, 0);
      }
    }

    float sv[4][4];
    float mt = -1e30f;
#pragma unroll
    for (int jb = 0; jb < 4; jb++)
#pragma unroll
      for (int i = 0; i < 4; i++) {
        int kkI = kt0 + jb*16 + lg*4 + i;
        float s = sacc[jb][i] * scale;
        if (kkI >= SEQ) s = -1e30f;
        sv[jb][i] = s;
        mt = fmaxf(mt, s);
      }
    mt = fmaxf(mt, __shfl_xor(mt, 16));
    mt = fmaxf(mt, __shfl_xor(mt, 32));
    float mnew = fmaxf(mreg, mt);
    float alpha = expf(mreg - mnew);
    float rs = 0.f;
#pragma unroll
    for (int jb = 0; jb < 4; jb++)
#pragma unroll
      for (int i = 0; i < 4; i++) {
        float p = expf(sv[jb][i] - mnew);
        sv[jb][i] = p; rs += p;
      }
    rs += __shfl_xor(rs, 16);
    rs += __shfl_xor(rs, 32);
    lsum = lsum * alpha + rs;
    mreg = mnew;

    unsigned pk[4][2];
#pragma unroll
    for (int jb = 0; jb < 4; jb++) {
      unsigned short c0 = __builtin_bit_cast(unsigned short, (__bf16)sv[jb][0]);
      unsigned short c1 = __builtin_bit_cast(unsigned short, (__bf16)sv[jb][1]);
      unsigned short c2 = __builtin_bit_cast(unsigned short, (__bf16)sv[jb][2]);
      unsigned short c3 = __builtin_bit_cast(unsigned short, (__bf16)sv[jb][3]);
      pk[jb][0] = ((unsigned)c1 << 16) | c0;
      pk[jb][1] = ((unsigned)c3 << 16) | c2;
    }

    float al0 = __shfl(alpha, lg*4 + 0);
    float al1 = __shfl(alpha, lg*4 + 1);
    float al2 = __shfl(alpha, lg*4 + 2);
    float al3 = __shfl(alpha, lg*4 + 3);
#pragma unroll
    for (int db = 0; db < 8; db++) {
      Oacc[db][0] *= al0; Oacc[db][1] *= al1; Oacc[db][2] *= al2; Oacc[db][3] *= al3;
    }

    int srcA = lr + ((lg & 1) << 5);
    int srcB = srcA + 16;
    bool hiSel = (lg >> 1) != 0;
#pragma unroll
    for (int c = 0; c < 2; c++) {
      int a00 = __shfl((int)pk[2*c][0], srcA);
      int a01 = __shfl((int)pk[2*c][1], srcA);
      int a10 = __shfl((int)pk[2*c+1][0], srcA);
      int a11 = __shfl((int)pk[2*c+1][1], srcA);
      int b00 = __shfl((int)pk[2*c][0], srcB);
      int b01 = __shfl((int)pk[2*c][1], srcB);
      int b10 = __shfl((int)pk[2*c+1][0], srcB);
      int b11 = __shfl((int)pk[2*c+1][1], srcB);
      int4 pa;
      pa.x = hiSel ? a10 : a00;
      pa.y = hiSel ? a11 : a01;
      pa.z = hiSel ? b10 : b00;
      pa.w = hiSel ? b11 : b01;
      bf16x8 paf = __builtin_bit_cast(bf16x8, pa);
#pragma unroll
      for (int db = 0; db < 8; db++) {
        int d = db*16 + lr;
        int byte = (d*128 + (c*32 + lg*8)*2) ^ ((lr & 7) << 4);
        bf16x8 bfv = *(const bf16x8*)((const char*)Vt + byte);
        Oacc[db] = __builtin_amdgcn_mfma_f32_16x16x32_bf16(paf, bfv, Oacc[db], 0, 0, 0);
      }
    }
  }

  float l0 = __shfl(lsum, lg*4 + 0);
  float l1 = __shfl(lsum, lg*4 + 1);
  float l2 = __shfl(lsum, lg*4 + 2);
  float l3 = __shfl(lsum, lg*4 + 3);
  float inv[4] = {1.f/l0, 1.f/l1, 1.f/l2, 1.f/l3};
#pragma unroll
  for (int i = 0; i < 4; i++) {
    int tok = qt*64 + wid*16 + lg*4 + i;
    if (tok < SEQ) {
      __bf16* dst = o + ((size_t)(b*SEQ + tok))*DMODEL + hh*DHEAD + lr;
#pragma unroll
      for (int db = 0; db < 8; db++) dst[db*16] = (__bf16)(Oacc[db][i] * inv[i]);
    }
  }
}

// ---------------------------------------------------------------- MoE gating (softmax + top-4)
__global__ void moe_gate(const float* __restrict__ m, const float* __restrict__ wg,
                         const float* __restrict__ bg, int* __restrict__ idx,
                         float* __restrict__ gate) {
  int t = blockIdx.x, tid = threadIdx.x;
  __shared__ __align__(16) float xs[DMODEL];
  __shared__ float probs[32];
  ((float4*)xs)[tid] = ((const float4*)(m + (size_t)t*DMODEL))[tid];
  __syncthreads();
  int e = tid >> 3, sub = tid & 7;
  if (e < NEXP) {
    float p = 0.f;
    for (int d = sub; d < DMODEL; d += 8) p = fmaf(xs[d], wg[d*NEXP + e], p);
    p += __shfl_down(p, 4, 8);
    p += __shfl_down(p, 2, 8);
    p += __shfl_down(p, 1, 8);
    if (sub == 0) probs[e] = p + bg[e];
  }
  __syncthreads();
  if (tid == 0) {
    float mx = probs[0];
    for (int i = 1; i < NEXP; i++) mx = fmaxf(mx, probs[i]);
    float ssum = 0.f;
    for (int i = 0; i < NEXP; i++) { probs[i] = expf(probs[i]-mx); ssum += probs[i]; }
    float invs = 1.f / ssum;
    float gv[TOPK]; int gi[TOPK]; float gsum = 0.f;
    for (int kk = 0; kk < TOPK; kk++) {
      float best = -1.f; int bi = 0;
      for (int i = 0; i < NEXP; i++) if (probs[i] > best) { best = probs[i]; bi = i; }
      gv[kk] = best * invs; gi[kk] = bi; probs[bi] = -1.f; gsum += gv[kk];
    }
    float ginv = 1.f / gsum;
    for (int kk = 0; kk < TOPK; kk++) { idx[t*TOPK+kk] = gi[kk]; gate[t*TOPK+kk] = gv[kk]*ginv; }
  }
}

// ---------------------------------------------------------------- MoE dispatch (ballot scan)
__global__ void moe_dispatch(const int* __restrict__ idx, int* __restrict__ slot,
                             int* __restrict__ rowmap, int* __restrict__ cnt) {
  int e = blockIdx.x, tid = threadIdx.x;
  int lane = tid & 63, wid = tid >> 6;
  __shared__ int wsum[4];
  int base = 0;
  for (int c0 = 0; c0 < TKF; c0 += 256) {
    int f = c0 + tid;
    int match = (f < TKF && idx[f] == e) ? 1 : 0;
    unsigned long long bal = __ballot(match);
    if (lane == 0) wsum[wid] = __popcll(bal);
    __syncthreads();
    int prefix = 0;
#pragma unroll
    for (int w2 = 0; w2 < 4; w2++) if (w2 < wid) prefix += wsum[w2];
    int total = wsum[0] + wsum[1] + wsum[2] + wsum[3];
    if (match) {
      int pos = base + prefix + __popcll(bal & ((1ull << lane) - 1ull));
      if (pos < CAPACITY) { slot[f] = pos; rowmap[e*CAPACITY + pos] = f; }
      else slot[f] = -1;
    }
    base += total;
    __syncthreads();
  }
  if (tid == 0) cnt[e] = (base < CAPACITY) ? base : CAPACITY;
}

// ---------------------------------------------------------------- MoE combine
__global__ void moe_sum(const float* __restrict__ y, const int* __restrict__ slot,
                        float* __restrict__ h) {
  int t = blockIdx.x, d4 = threadIdx.x;
  float4 acc = ((float4*)(h + (size_t)t*DMODEL))[d4];
#pragma unroll
  for (int kk = 0; kk < TOPK; kk++) {
    int f = t*TOPK + kk;
    if (slot[f] >= 0) {
      float4 yv = ((const float4*)(y + (size_t)f*DMODEL))[d4];
      acc.x += yv.x; acc.y += yv.y; acc.z += yv.z; acc.w += yv.w;
    }
  }
  ((float4*)(h + (size_t)t*DMODEL))[d4] = acc;
}

// ---------------------------------------------------------------- final output
__global__ void final_copy(const float* __restrict__ h, float* __restrict__ out) {
  int b = blockIdx.x, tid = threadIdx.x;
  float4 v = ((const float4*)(h + (size_t)b*SEQ*DMODEL))[tid];
  ((float4*)(out + (size_t)b*DMODEL))[tid] = v;
}

// ---------------------------------------------------------------- host
extern "C" void kernel_launch(void* const* d_in, const int* in_sizes, int n_in,
                              void* d_out, int out_size, void* d_ws, size_t ws_size,
                              hipStream_t stream) {
  (void)in_sizes; (void)n_in; (void)out_size; (void)ws_size;
  const float* x         = (const float*)d_in[0];
  const float* conv_w1   = (const float*)d_in[1];
  const float* conv_w2   = (const float*)d_in[2];
  const float* conv_w3   = (const float*)d_in[3];
  const float* bn1_g     = (const float*)d_in[4];
  const float* bn1_b     = (const float*)d_in[5];
  const float* bn2_g     = (const float*)d_in[6];
  const float* bn2_b     = (const float*)d_in[7];
  const float* bn3_g     = (const float*)d_in[8];
  const float* bn3_b     = (const float*)d_in[9];
  const float* proj_w    = (const float*)d_in[10];
  const float* proj_b    = (const float*)d_in[11];
  const float* cls_token = (const float*)d_in[12];
  const float* mask_tok  = (const float*)d_in[13];
  const float* ln1_g     = (const float*)d_in[14];
  const float* ln1_b     = (const float*)d_in[15];
  const float* ln2_g     = (const float*)d_in[16];
  const float* ln2_b     = (const float*)d_in[17];
  const float* wq        = (const float*)d_in[18];
  const float* wk        = (const float*)d_in[19];
  const float* wv        = (const float*)d_in[20];
  const float* wo        = (const float*)d_in[21];
  const float* bq        = (const float*)d_in[22];
  const float* bk        = (const float*)d_in[23];
  const float* bv        = (const float*)d_in[24];
  const float* bo        = (const float*)d_in[25];
  const float* wg        = (const float*)d_in[26];
  const float* bg        = (const float*)d_in[27];
  const float* we1       = (const float*)d_in[28];
  const float* be1       = (const float*)d_in[29];
  const float* we2       = (const float*)d_in[30];
  const float* be2       = (const float*)d_in[31];
  float* out = (float*)d_out;

  char* base = (char*)d_ws;
  const size_t TDB = (size_t)NTOK * DMODEL * 4;         // 16.8 MB
  float*  h    = (float*)(base);                        // 1 TDB
  float*  xbuf = (float*)(base + TDB);                  // 1 TDB
  float*  yb   = (float*)(base + 2*TDB);                // 4 TDB (TKF*1024 f32)
  __bf16* xbf  = (__bf16*)(base + 6*TDB);               // 0.5 TDB
  __bf16* ao   = (__bf16*)(base + 6*TDB + TDB/2);       // 0.5 TDB
  __bf16* qkvb = (__bf16*)(base + 7*TDB);               // 1.5 TDB (NTOK x 3072 bf16)
  __bf16* hid  = (__bf16*)(base + 8*TDB + TDB/2);       // 2 TDB (TKF*1024 bf16)
  char* misc   = base + 11*TDB;
  float* feat  = (float*)misc;                          // NBINTOT*64
  float* gate  = feat + (size_t)NBINTOT*64;
  int* idx     = (int*)(gate + TKF);
  int* slot    = idx + TKF;
  int* rowmap  = slot + TKF;
  int* cnt     = rowmap + NEXP*CAPACITY;
  int* msk     = cnt + 32;
  char* wtb    = base + 12*TDB;                          // weight area
  const size_t MB1 = (size_t)1024*1024;                  // elems per matrix
  __bf16* wqkv = (__bf16*)wtb;                           // [L][3][1024][1024] packed
  __bf16* wto  = wqkv + 12*MB1;                          // 4 mats
  __bf16* wte1 = wto + 4*MB1;                            // 120 mats
  __bf16* wte2 = wte1 + 120*MB1;                         // 120 mats

  // ---- weight convert+transpose to bf16 [n][k]; QKV packed per layer
  transpose_w<<<dim3(256, 4),   256, 0, stream>>>(wq,  wqkv,           3*MB1);
  transpose_w<<<dim3(256, 4),   256, 0, stream>>>(wk,  wqkv + MB1,     3*MB1);
  transpose_w<<<dim3(256, 4),   256, 0, stream>>>(wv,  wqkv + 2*MB1,   3*MB1);
  transpose_w<<<dim3(256, 4),   256, 0, stream>>>(wo,  wto,            MB1);
  transpose_w<<<dim3(256, 120), 256, 0, stream>>>(we1, wte1,           MB1);
  transpose_w<<<dim3(256, 120), 256, 0, stream>>>(we2, wte2,           MB1);

  conv_frontend<<<NBINTOT, 64, 0, stream>>>(x, conv_w1, conv_w2, conv_w3,
      bn1_g, bn1_b, bn2_g, bn2_b, bn3_g, bn3_b, feat, msk);
  embed_kernel<<<dim3(SEQ, BATCH), 256, 0, stream>>>(feat, msk, proj_w, proj_b,
      cls_token, mask_tok, h);

  dim3 gqkv((NTOK + 127)/128, 24);       // 33 x 24  (N=3072, 128-col tiles)
  dim3 gwo((NTOK + 127)/128, 8);         // 33 x 8
  dim3 gmoe(NEXP*9, 8);                  // 270 x 8

  for (int l = 0; l < NLAYER; l++) {
    __bf16* wqkv_l = wqkv + (size_t)l*3*MB1;
    __bf16* wto_l  = wto  + (size_t)l*MB1;
    __bf16* wte1_l = wte1 + (size_t)l*NEXP*MB1;
    __bf16* wte2_l = wte2 + (size_t)l*NEXP*MB1;

    ln_kernel<<<NTOK, 256, 0, stream>>>(h, xbuf, xbf, ln1_g + (size_t)l*DMODEL, ln1_b + (size_t)l*DMODEL);
    gemm_bf16<0,0><<<gqkv, 512, 0, stream>>>(xbf, wqkv_l,
        bq + (size_t)l*DMODEL, bk + (size_t)l*DMODEL, bv + (size_t)l*DMODEL,
        qkvb, NTOK, nullptr, nullptr, nullptr);
    attn_mfma<<<dim3(9, BATCH*NHEAD), 256, 0, stream>>>(qkvb, ao);
    gemm_bf16<1,0><<<gwo, 512, 0, stream>>>(ao, wto_l,
        bo + (size_t)l*DMODEL, nullptr, nullptr, h, NTOK, nullptr, nullptr, nullptr);
    ln_kernel<<<NTOK, 256, 0, stream>>>(h, xbuf, xbf, ln2_g + (size_t)l*DMODEL, ln2_b + (size_t)l*DMODEL);
    moe_gate<<<NTOK, 256, 0, stream>>>(xbuf, wg + (size_t)l*DMODEL*NEXP, bg + (size_t)l*NEXP, idx, gate);
    moe_dispatch<<<NEXP, 256, 0, stream>>>(idx, slot, rowmap, cnt);
    gemm_bf16<2,1><<<gmoe, 512, 0, stream>>>(xbf, wte1_l,
        be1 + (size_t)l*NEXP*1024, nullptr, nullptr, hid, 0, rowmap, cnt, nullptr);
    gemm_bf16<3,1><<<gmoe, 512, 0, stream>>>(hid, wte2_l,
        be2 + (size_t)l*NEXP*1024, nullptr, nullptr, yb, 0, rowmap, cnt, gate);
    moe_sum<<<NTOK, 256, 0, stream>>>(yb, slot, h);
  }
  final_copy<<<BATCH, 256, 0, stream>>>(h, out);
}

// Round 12
// 2676.963 us; speedup vs baseline: 1.1062x; 1.1062x over previous
//
#include <hip/hip_runtime.h>
#include <hip/hip_bf16.h>
#include <math.h>

#define BATCH   8
#define NBINS   512
#define BINSZ   10
#define DMODEL  1024
#define NHEAD   8
#define DHEAD   128
#define NLAYER  4
#define NEXP    30
#define TOPK    4
#define SEQ     513            // NBINS + 1
#define NTOK    (BATCH*SEQ)    // 4104
#define NBINTOT (BATCH*NBINS)  // 4096
#define CAPACITY 1152
#define TKF     (NTOK*TOPK)    // 16416
#define QKVLD   3072           // packed qkv row stride

typedef __attribute__((ext_vector_type(8))) __bf16 bf16x8;
typedef __attribute__((ext_vector_type(4))) __bf16 bf16x4;
typedef __attribute__((ext_vector_type(4))) float f32x4;

__device__ __forceinline__ float gelu_f(float x) {
  return 0.5f * x * (1.0f + erff(x * 0.7071067811865475f));
}

__device__ __forceinline__ bf16x8 bf8_zero() {
  int4 z = make_int4(0, 0, 0, 0);
  return __builtin_bit_cast(bf16x8, z);
}

// ---------------------------------------------------------------- weight convert + transpose
__global__ __launch_bounds__(256) void transpose_w(const float* __restrict__ src,
                                                   __bf16* __restrict__ dst, size_t mstride) {
  int mat = blockIdx.y;
  int tile = blockIdx.x;          // 0..255
  int kt = (tile >> 4) * 64;
  int nt = (tile & 15) * 64;
  const float* s = src + (size_t)mat * 1024 * 1024;
  __bf16* d = dst + (size_t)mat * mstride;
  __shared__ float t[64][65];
  int tid = threadIdx.x;
  int r = tid >> 4, c4 = (tid & 15) * 4;
#pragma unroll
  for (int i = 0; i < 4; i++) {
    float4 v = *(const float4*)(s + (size_t)(kt + r + i*16) * 1024 + nt + c4);
    t[r + i*16][c4+0] = v.x; t[r + i*16][c4+1] = v.y;
    t[r + i*16][c4+2] = v.z; t[r + i*16][c4+3] = v.w;
  }
  __syncthreads();
  int r2 = tid >> 2, c2 = (tid & 3) * 16;
  bf16x8 o0, o1;
#pragma unroll
  for (int j = 0; j < 8; j++) { o0[j] = (__bf16)t[c2+j][r2]; o1[j] = (__bf16)t[c2+8+j][r2]; }
  *(bf16x8*)(d + (size_t)(nt + r2) * 1024 + kt + c2)     = o0;
  *(bf16x8*)(d + (size_t)(nt + r2) * 1024 + kt + c2 + 8) = o1;
}

// ---------------------------------------------------------------- conv frontend (named-scalar accs)
#define CSTEP(acc, T, DIL, hr, wA, wB, wC) { \
  float vv_ = (wB) * (hr)[T]; \
  if ((T) >= (DIL)) vv_ = fmaf((wA), (hr)[(T)-(DIL)], vv_); \
  if ((T) + (DIL) <= 9) vv_ = fmaf((wC), (hr)[(T)+(DIL)], vv_); \
  acc += vv_; }

#define CALL10(DIL, hr, wA, wB, wC) \
  CSTEP(t0,0,DIL,hr,wA,wB,wC); CSTEP(t1,1,DIL,hr,wA,wB,wC); \
  CSTEP(t2,2,DIL,hr,wA,wB,wC); CSTEP(t3,3,DIL,hr,wA,wB,wC); \
  CSTEP(t4,4,DIL,hr,wA,wB,wC); CSTEP(t5,5,DIL,hr,wA,wB,wC); \
  CSTEP(t6,6,DIL,hr,wA,wB,wC); CSTEP(t7,7,DIL,hr,wA,wB,wC); \
  CSTEP(t8,8,DIL,hr,wA,wB,wC); CSTEP(t9,9,DIL,hr,wA,wB,wC);

#define ZERO10 float t0=0.f,t1=0.f,t2=0.f,t3=0.f,t4=0.f,t5=0.f,t6=0.f,t7=0.f,t8=0.f,t9=0.f;

#define STORE10(dst, sc, sh) \
  (dst)[0]=gelu_f(t0*(sc)+(sh)); (dst)[1]=gelu_f(t1*(sc)+(sh)); \
  (dst)[2]=gelu_f(t2*(sc)+(sh)); (dst)[3]=gelu_f(t3*(sc)+(sh)); \
  (dst)[4]=gelu_f(t4*(sc)+(sh)); (dst)[5]=gelu_f(t5*(sc)+(sh)); \
  (dst)[6]=gelu_f(t6*(sc)+(sh)); (dst)[7]=gelu_f(t7*(sc)+(sh)); \
  (dst)[8]=gelu_f(t8*(sc)+(sh)); (dst)[9]=gelu_f(t9*(sc)+(sh));

__global__ __launch_bounds__(64) void conv_frontend(const float* __restrict__ x,
                              const float* __restrict__ w1, const float* __restrict__ w2,
                              const float* __restrict__ w3,
                              const float* __restrict__ g1, const float* __restrict__ b1,
                              const float* __restrict__ g2, const float* __restrict__ b2,
                              const float* __restrict__ g3, const float* __restrict__ b3,
                              float* __restrict__ feat, int* __restrict__ msk) {
  const float bnscale = 0.9999950000374997f;   // 1/sqrt(1+1e-5)
  int bin = blockIdx.x;
  int c = threadIdx.x;
  __shared__ float xs[BINSZ];
  __shared__ float h1[16][BINSZ];
  __shared__ float h2[32][BINSZ];
  if (c < BINSZ) xs[c] = x[bin*BINSZ + c];
  if (c == 0) {
    int all = 1;
    for (int t = 0; t < BINSZ; t++) if (x[bin*BINSZ+t] != -100.0f) { all = 0; break; }
    msk[bin] = all;
  }
  __syncthreads();
  if (c < 16) {
    float sc = g1[c]*bnscale, sh = b1[c];
    float wA = w1[c*3], wB = w1[c*3+1], wC = w1[c*3+2];
    const float* hr = &xs[0];
    ZERO10;
    CALL10(1, hr, wA, wB, wC);
    STORE10(&h1[c][0], sc, sh);
  }
  __syncthreads();
  if (c < 32) {
    float sc = g2[c]*bnscale, sh = b2[c];
    ZERO10;
    for (int ci = 0; ci < 16; ci++) {
      const float* w = w2 + (c*16+ci)*3;
      float wA = w[0], wB = w[1], wC = w[2];
      const float* hr = &h1[ci][0];
      CALL10(2, hr, wA, wB, wC);
    }
    STORE10(&h2[c][0], sc, sh);
  }
  __syncthreads();
  {
    float sc = g3[c]*bnscale, sh = b3[c];
    ZERO10;
    for (int ci = 0; ci < 32; ci++) {
      const float* w = w3 + (c*32+ci)*3;
      float wA = w[0], wB = w[1], wC = w[2];
      const float* hr = &h2[ci][0];
      CALL10(4, hr, wA, wB, wC);
    }
    float mean = gelu_f(t0*sc+sh) + gelu_f(t1*sc+sh) + gelu_f(t2*sc+sh)
               + gelu_f(t3*sc+sh) + gelu_f(t4*sc+sh) + gelu_f(t5*sc+sh)
               + gelu_f(t6*sc+sh) + gelu_f(t7*sc+sh) + gelu_f(t8*sc+sh)
               + gelu_f(t9*sc+sh);
    feat[bin*64 + c] = mean * 0.1f;
  }
}

// ---------------------------------------------------------------- embed + PE
__global__ void embed_kernel(const float* __restrict__ feat, const int* __restrict__ msk,
                             const float* __restrict__ proj_w, const float* __restrict__ proj_b,
                             const float* __restrict__ cls_token, const float* __restrict__ mask_token,
                             float* __restrict__ h) {
  int s_ = blockIdx.x;
  int b  = blockIdx.y;
  int tid = threadIdx.x;
  __shared__ __align__(16) float fs[64];
  float out[4];
  if (s_ == 0) {
#pragma unroll
    for (int u = 0; u < 4; u++) out[u] = cls_token[tid*4+u];
  } else {
    int bin = b*NBINS + (s_-1);
    if (tid < 16) ((float4*)fs)[tid] = ((const float4*)(feat + (size_t)bin*64))[tid];
    __syncthreads();
    int m_ = msk[bin];
#pragma unroll
    for (int u = 0; u < 4; u++) {
      int d = tid*4+u;
      float acc = proj_b[d];
      for (int ci = 0; ci < 64; ci++) acc = fmaf(fs[ci], proj_w[ci*DMODEL + d], acc);
      out[u] = m_ ? mask_token[d] : acc;
    }
  }
  const float c0 = -0.008994473019507992f;  // -ln(10000)/1024
#pragma unroll
  for (int u = 0; u < 4; u++) {
    int d = tid*4+u;
    float div = expf(c0 * (float)(d & ~1));
    float ang = (float)s_ * div;
    float pe = (d & 1) ? cosf(ang) : sinf(ang);
    h[((size_t)(b*SEQ + s_))*DMODEL + d] = out[u] + pe;
  }
}

// ---------------------------------------------------------------- layernorm -> bf16 only (ln1)
__global__ void ln_kernel(const float* __restrict__ x, __bf16* __restrict__ outb,
                          const float* __restrict__ g, const float* __restrict__ b) {
  int t = blockIdx.x, tid = threadIdx.x;
  float4 v = ((const float4*)(x + (size_t)t*DMODEL))[tid];
  float s  = v.x+v.y+v.z+v.w;
  float sq = v.x*v.x+v.y*v.y+v.z*v.z+v.w*v.w;
  for (int off = 32; off; off >>= 1) { s += __shfl_down(s, off); sq += __shfl_down(sq, off); }
  __shared__ float ss[4], ssq[4], mv[2];
  int w = tid >> 6, l = tid & 63;
  if (l == 0) { ss[w] = s; ssq[w] = sq; }
  __syncthreads();
  if (tid == 0) {
    float a = 0, c = 0;
    for (int i = 0; i < 4; i++) { a += ss[i]; c += ssq[i]; }
    float mean = a * (1.f/DMODEL);
    float var  = c * (1.f/DMODEL) - mean*mean;
    mv[0] = mean; mv[1] = rsqrtf(var + 1e-5f);
  }
  __syncthreads();
  float mean = mv[0], inv = mv[1];
  float4 gg = ((const float4*)g)[tid];
  float4 bb = ((const float4*)b)[tid];
  float4 o;
  o.x = (v.x-mean)*inv*gg.x + bb.x;
  o.y = (v.y-mean)*inv*gg.y + bb.y;
  o.z = (v.z-mean)*inv*gg.z + bb.z;
  o.w = (v.w-mean)*inv*gg.w + bb.w;
  bf16x4 ob;
  ob[0] = (__bf16)o.x; ob[1] = (__bf16)o.y; ob[2] = (__bf16)o.z; ob[3] = (__bf16)o.w;
  *(bf16x4*)(outb + (size_t)t*DMODEL + tid*4) = ob;
}

// ---------------------------------------------------------------- fused LN2 + MoE gating
// LN result kept in LDS (fp32 identical to old xbuf); gating reads LDS, not HBM.
__global__ void ln_gate(const float* __restrict__ x, __bf16* __restrict__ outb,
                        const float* __restrict__ g, const float* __restrict__ b,
                        const float* __restrict__ wg, const float* __restrict__ bg,
                        int* __restrict__ idx, float* __restrict__ gate) {
  int t = blockIdx.x, tid = threadIdx.x;
  __shared__ __align__(16) float xs[DMODEL];
  __shared__ float ss[4], ssq[4], mv[2];
  __shared__ float probs[32];
  float4 v = ((const float4*)(x + (size_t)t*DMODEL))[tid];
  float s  = v.x+v.y+v.z+v.w;
  float sq = v.x*v.x+v.y*v.y+v.z*v.z+v.w*v.w;
  for (int off = 32; off; off >>= 1) { s += __shfl_down(s, off); sq += __shfl_down(sq, off); }
  int w = tid >> 6, l = tid & 63;
  if (l == 0) { ss[w] = s; ssq[w] = sq; }
  __syncthreads();
  if (tid == 0) {
    float a = 0, c = 0;
    for (int i = 0; i < 4; i++) { a += ss[i]; c += ssq[i]; }
    float mean = a * (1.f/DMODEL);
    float var  = c * (1.f/DMODEL) - mean*mean;
    mv[0] = mean; mv[1] = rsqrtf(var + 1e-5f);
  }
  __syncthreads();
  float mean = mv[0], inv = mv[1];
  float4 gg = ((const float4*)g)[tid];
  float4 bb = ((const float4*)b)[tid];
  float4 o;
  o.x = (v.x-mean)*inv*gg.x + bb.x;
  o.y = (v.y-mean)*inv*gg.y + bb.y;
  o.z = (v.z-mean)*inv*gg.z + bb.z;
  o.w = (v.w-mean)*inv*gg.w + bb.w;
  bf16x4 ob;
  ob[0] = (__bf16)o.x; ob[1] = (__bf16)o.y; ob[2] = (__bf16)o.z; ob[3] = (__bf16)o.w;
  *(bf16x4*)(outb + (size_t)t*DMODEL + tid*4) = ob;
  ((float4*)xs)[tid] = o;
  __syncthreads();
  int e = tid >> 3, sub = tid & 7;
  if (e < NEXP) {
    float p = 0.f;
    for (int d = sub; d < DMODEL; d += 8) p = fmaf(xs[d], wg[d*NEXP + e], p);
    p += __shfl_down(p, 4, 8);
    p += __shfl_down(p, 2, 8);
    p += __shfl_down(p, 1, 8);
    if (sub == 0) probs[e] = p + bg[e];
  }
  __syncthreads();
  if (tid == 0) {
    float mx = probs[0];
    for (int i = 1; i < NEXP; i++) mx = fmaxf(mx, probs[i]);
    float ssum = 0.f;
    for (int i = 0; i < NEXP; i++) { probs[i] = expf(probs[i]-mx); ssum += probs[i]; }
    float invs = 1.f / ssum;
    float gv[TOPK]; int gi[TOPK]; float gsum = 0.f;
    for (int kk = 0; kk < TOPK; kk++) {
      float best = -1.f; int bi = 0;
      for (int i = 0; i < NEXP; i++) if (probs[i] > best) { best = probs[i]; bi = i; }
      gv[kk] = best * invs; gi[kk] = bi; probs[bi] = -1.f; gsum += gv[kk];
    }
    float ginv = 1.f / gsum;
    for (int kk = 0; kk < TOPK; kk++) { idx[t*TOPK+kk] = gi[kk]; gate[t*TOPK+kk] = gv[kk]*ginv; }
  }
}

// ---------------------------------------------------------------- bf16 MFMA GEMM, 128x128 tile, reg-prefetch (R9 core)
// MODE 0: fused QKV — Wt [3072][1024], C bf16 row-stride 3072, bias per 1024-window
// MODE 1: WO residual — C f32 +=
// MODE 2: MoE ffn1 — gather f>>2, gelu -> hid bf16
// MODE 3: MoE ffn2 — gather f, gate -> yb bf16
template<int MODE>
__global__ __launch_bounds__(512) void gemm_bf16(
    const __bf16* __restrict__ A, const __bf16* __restrict__ Wt,
    const float* __restrict__ b0, const float* __restrict__ b1, const float* __restrict__ b2,
    void* __restrict__ C, int M,
    const int* __restrict__ rowmap, const int* __restrict__ cnt,
    const float* __restrict__ gate) {
  int tid = threadIdx.x;
  int rowbase, validrows, e = 0;
  const __bf16* Wb = Wt;
  if (MODE <= 1) {
    rowbase = blockIdx.x * 128;
    validrows = M - rowbase; if (validrows > 128) validrows = 128;
  } else {
    e = blockIdx.x / 9;
    int p0 = (blockIdx.x % 9) * 128;
    int ce = cnt[e];
    if (p0 >= ce) return;
    rowbase = p0;
    validrows = ce - p0; if (validrows > 128) validrows = 128;
    Wb = Wt + (size_t)e * 1024 * 1024;
  }
  int colbase = blockIdx.y * 128;

  __shared__ __align__(16) __bf16 As[4][128][8];   // [kgroup][row][8k]
  __shared__ __align__(16) __bf16 Bs[4][128][8];   // [kgroup][col][8k]
  __shared__ int srcrow[128];
  __shared__ int frow[128];

  if (tid < 128) {
    if (MODE <= 1) { srcrow[tid] = rowbase + tid; frow[tid] = rowbase + tid; }
    else if (tid < validrows) {
      int f = rowmap[e*CAPACITY + rowbase + tid];
      frow[tid] = f;
      srcrow[tid] = (MODE == 2) ? (f >> 2) : f;
    } else { frow[tid] = 0; srcrow[tid] = 0; }
  }
  __syncthreads();

  int arow = tid >> 2, ag = tid & 3;            // A: row, k-group (8 bf16 each)
  int wcol = tid & 127, wgp = tid >> 7;         // W: col, k-group
  bool aval = (arow < validrows);
  const __bf16* Ap = A + (size_t)srcrow[arow] * 1024 + ag * 8;
  const __bf16* Wp = Wb + (size_t)(colbase + wcol) * 1024 + wgp * 8;

  int w  = tid >> 6;
  int wr = w & 3, wc = w >> 2;        // wave quadrant: rows wr*32.., cols wc*64..
  int l  = tid & 63;
  int lr = l & 15, lg = l >> 4;

  f32x4 acc[2][4] = {};

  bf16x8 areg = bf8_zero(), breg;
  if (aval) areg = *(const bf16x8*)(Ap);
  breg = *(const bf16x8*)(Wp);

  for (int kt = 0; kt < 1024; kt += 32) {
    __syncthreads();
    *(bf16x8*)&As[ag][arow][0] = areg;
    *(bf16x8*)&Bs[wgp][wcol][0] = breg;
    __syncthreads();

    if (kt + 32 < 1024) {
      if (aval) areg = *(const bf16x8*)(Ap + kt + 32);
      breg = *(const bf16x8*)(Wp + kt + 32);
    }

    bf16x8 af[2], bfr[4];
    af[0] = *(const bf16x8*)&As[lg][wr*32 + lr][0];
    af[1] = *(const bf16x8*)&As[lg][wr*32 + 16 + lr][0];
#pragma unroll
    for (int fj = 0; fj < 4; fj++) bfr[fj] = *(const bf16x8*)&Bs[lg][wc*64 + fj*16 + lr][0];
#pragma unroll
    for (int fi = 0; fi < 2; fi++)
#pragma unroll
      for (int fj = 0; fj < 4; fj++)
        acc[fi][fj] = __builtin_amdgcn_mfma_f32_16x16x32_bf16(af[fi], bfr[fj], acc[fi][fj], 0, 0, 0);
  }

  // epilogue: C/D layout col = l&15, row = (l>>4)*4 + i
  if (MODE == 0) {
    int which = colbase >> 10;              // block-uniform
    int colb0 = colbase & 1023;
    const float* bsel = (which == 0) ? b0 : (which == 1) ? b1 : b2;
#pragma unroll
    for (int fj = 0; fj < 4; fj++) {
      int col = wc*64 + fj*16 + lr;
      float bvv = bsel[colb0 + col];
#pragma unroll
      for (int fi = 0; fi < 2; fi++)
#pragma unroll
        for (int i = 0; i < 4; i++) {
          int r = wr*32 + fi*16 + lg*4 + i;
          if (r >= validrows) continue;
          ((__bf16*)C)[(size_t)(rowbase + r)*QKVLD + colbase + col] = (__bf16)(acc[fi][fj][i] + bvv);
        }
    }
  } else {
    const float* bptr = (MODE >= 2) ? (b0 + (size_t)e * 1024) : b0;
#pragma unroll
    for (int fj = 0; fj < 4; fj++) {
      int col = wc*64 + fj*16 + lr;
      float bvv = bptr[colbase + col];
#pragma unroll
      for (int fi = 0; fi < 2; fi++)
#pragma unroll
        for (int i = 0; i < 4; i++) {
          int r = wr*32 + fi*16 + lg*4 + i;
          if (r >= validrows) continue;
          float val = acc[fi][fj][i] + bvv;
          if (MODE == 1) {
            float* p = (float*)C + (size_t)(rowbase + r)*1024 + colbase + col;
            *p = *p + val;
          } else if (MODE == 2) {
            ((__bf16*)C)[(size_t)frow[r]*1024 + colbase + col] = (__bf16)gelu_f(val);
          } else {
            ((__bf16*)C)[(size_t)frow[r]*1024 + colbase + col] = (__bf16)(gate[frow[r]] * val);
          }
        }
    }
  }
}

// ---------------------------------------------------------------- MFMA flash attention (packed qkv, stride 3072)
__global__ __launch_bounds__(256) void attn_mfma(const __bf16* __restrict__ qkv,
                                                 __bf16* __restrict__ o) {
  int qt = blockIdx.x;
  int bh = blockIdx.y;
  int b = bh >> 3, hh = bh & 7;
  int tid = threadIdx.x;
  int wid = tid >> 6, l = tid & 63;
  int lr = l & 15, lg = l >> 4;

  __shared__ __align__(16) __bf16 Ks[64*128];   // [kk][d] row-major, swizzled
  __shared__ __align__(16) __bf16 Vt[128*64];   // [d][kk] row-major, swizzled

  const float scale = 0.08838834764831845f;  // 1/sqrt(128)

  int qtok = qt*64 + wid*16 + lr;
  int qtokc = qtok < SEQ ? qtok : SEQ-1;
  const __bf16* qrow = qkv + (size_t)(b*SEQ + qtokc)*QKVLD + hh*DHEAD;
  bf16x8 qf[4];
#pragma unroll
  for (int c = 0; c < 4; c++) qf[c] = *(const bf16x8*)(qrow + c*32 + lg*8);

  float mreg = -1e30f, lsum = 0.f;
  f32x4 Oacc[8] = {};

  int krow = tid & 63, kdc = tid >> 6;   // K staging: row, 32-d chunk
  int vd = tid & 127, vkg0 = tid >> 7;   // V staging: d column, kk-group base

  for (int kt = 0; kt < 9; kt++) {
    int kt0 = kt*64;
    __syncthreads();
    {
      int tok = kt0 + krow; if (tok >= SEQ) tok = SEQ-1;
      const __bf16* kr = qkv + (size_t)(b*SEQ + tok)*QKVLD + 1024 + hh*DHEAD + kdc*32;
#pragma unroll
      for (int s2 = 0; s2 < 4; s2++) {
        bf16x8 t = *(const bf16x8*)(kr + s2*8);
        int byte = (krow*256 + (kdc*32 + s2*8)*2) ^ ((krow & 7) << 4);
        *(bf16x8*)((char*)Ks + byte) = t;
      }
    }
    {
#pragma unroll
      for (int it = 0; it < 4; it++) {
        int kkg = vkg0 + it*2;
        bf16x8 t;
#pragma unroll
        for (int j = 0; j < 8; j++) {
          int tok = kt0 + kkg*8 + j; if (tok >= SEQ) tok = SEQ-1;
          t[j] = qkv[(size_t)(b*SEQ + tok)*QKVLD + 2048 + hh*DHEAD + vd];
        }
        int byte = (vd*128 + kkg*16) ^ ((vd & 7) << 4);
        *(bf16x8*)((char*)Vt + byte) = t;
      }
    }
    __syncthreads();

    f32x4 sacc[4] = {};
#pragma unroll
    for (int c = 0; c < 4; c++) {
#pragma unroll
      for (int jb = 0; jb < 4; jb++) {
        int row = jb*16 + lr;
        int byte = (row*256 + (c*32 + lg*8)*2) ^ ((lr & 7) << 4);
        bf16x8 af = *(const bf16x8*)((const char*)Ks + byte);
        sacc[jb] = __builtin_amdgcn_mfma_f32_16x16x32_bf16(af, qf[c], sacc[jb], 0, 0, 0);
      }
    }

    float sv[4][4];
    float mt = -1e30f;
#pragma unroll
    for (int jb = 0; jb < 4; jb++)
#pragma unroll
      for (int i = 0; i < 4; i++) {
        int kkI = kt0 + jb*16 + lg*4 + i;
        float s = sacc[jb][i] * scale;
        if (kkI >= SEQ) s = -1e30f;
        sv[jb][i] = s;
        mt = fmaxf(mt, s);
      }
    mt = fmaxf(mt, __shfl_xor(mt, 16));
    mt = fmaxf(mt, __shfl_xor(mt, 32));
    float mnew = fmaxf(mreg, mt);
    float alpha = expf(mreg - mnew);
    float rs = 0.f;
#pragma unroll
    for (int jb = 0; jb < 4; jb++)
#pragma unroll
      for (int i = 0; i < 4; i++) {
        float p = expf(sv[jb][i] - mnew);
        sv[jb][i] = p; rs += p;
      }
    rs += __shfl_xor(rs, 16);
    rs += __shfl_xor(rs, 32);
    lsum = lsum * alpha + rs;
    mreg = mnew;

    unsigned pk[4][2];
#pragma unroll
    for (int jb = 0; jb < 4; jb++) {
      unsigned short c0 = __builtin_bit_cast(unsigned short, (__bf16)sv[jb][0]);
      unsigned short c1 = __builtin_bit_cast(unsigned short, (__bf16)sv[jb][1]);
      unsigned short c2 = __builtin_bit_cast(unsigned short, (__bf16)sv[jb][2]);
      unsigned short c3 = __builtin_bit_cast(unsigned short, (__bf16)sv[jb][3]);
      pk[jb][0] = ((unsigned)c1 << 16) | c0;
      pk[jb][1] = ((unsigned)c3 << 16) | c2;
    }

    float al0 = __shfl(alpha, lg*4 + 0);
    float al1 = __shfl(alpha, lg*4 + 1);
    float al2 = __shfl(alpha, lg*4 + 2);
    float al3 = __shfl(alpha, lg*4 + 3);
#pragma unroll
    for (int db = 0; db < 8; db++) {
      Oacc[db][0] *= al0; Oacc[db][1] *= al1; Oacc[db][2] *= al2; Oacc[db][3] *= al3;
    }

    int srcA = lr + ((lg & 1) << 5);
    int srcB = srcA + 16;
    bool hiSel = (lg >> 1) != 0;
#pragma unroll
    for (int c = 0; c < 2; c++) {
      int a00 = __shfl((int)pk[2*c][0], srcA);
      int a01 = __shfl((int)pk[2*c][1], srcA);
      int a10 = __shfl((int)pk[2*c+1][0], srcA);
      int a11 = __shfl((int)pk[2*c+1][1], srcA);
      int b00 = __shfl((int)pk[2*c][0], srcB);
      int b01 = __shfl((int)pk[2*c][1], srcB);
      int b10 = __shfl((int)pk[2*c+1][0], srcB);
      int b11 = __shfl((int)pk[2*c+1][1], srcB);
      int4 pa;
      pa.x = hiSel ? a10 : a00;
      pa.y = hiSel ? a11 : a01;
      pa.z = hiSel ? b10 : b00;
      pa.w = hiSel ? b11 : b01;
      bf16x8 paf = __builtin_bit_cast(bf16x8, pa);
#pragma unroll
      for (int db = 0; db < 8; db++) {
        int d = db*16 + lr;
        int byte = (d*128 + (c*32 + lg*8)*2) ^ ((lr & 7) << 4);
        bf16x8 bfv = *(const bf16x8*)((const char*)Vt + byte);
        Oacc[db] = __builtin_amdgcn_mfma_f32_16x16x32_bf16(paf, bfv, Oacc[db], 0, 0, 0);
      }
    }
  }

  float l0 = __shfl(lsum, lg*4 + 0);
  float l1 = __shfl(lsum, lg*4 + 1);
  float l2 = __shfl(lsum, lg*4 + 2);
  float l3 = __shfl(lsum, lg*4 + 3);
  float inv[4] = {1.f/l0, 1.f/l1, 1.f/l2, 1.f/l3};
#pragma unroll
  for (int i = 0; i < 4; i++) {
    int tok = qt*64 + wid*16 + lg*4 + i;
    if (tok < SEQ) {
      __bf16* dst = o + ((size_t)(b*SEQ + tok))*DMODEL + hh*DHEAD + lr;
#pragma unroll
      for (int db = 0; db < 8; db++) dst[db*16] = (__bf16)(Oacc[db][i] * inv[i]);
    }
  }
}

// ---------------------------------------------------------------- MoE dispatch (ballot scan)
__global__ void moe_dispatch(const int* __restrict__ idx, int* __restrict__ slot,
                             int* __restrict__ rowmap, int* __restrict__ cnt) {
  int e = blockIdx.x, tid = threadIdx.x;
  int lane = tid & 63, wid = tid >> 6;
  __shared__ int wsum[4];
  int base = 0;
  for (int c0 = 0; c0 < TKF; c0 += 256) {
    int f = c0 + tid;
    int match = (f < TKF && idx[f] == e) ? 1 : 0;
    unsigned long long bal = __ballot(match);
    if (lane == 0) wsum[wid] = __popcll(bal);
    __syncthreads();
    int prefix = 0;
#pragma unroll
    for (int w2 = 0; w2 < 4; w2++) if (w2 < wid) prefix += wsum[w2];
    int total = wsum[0] + wsum[1] + wsum[2] + wsum[3];
    if (match) {
      int pos = base + prefix + __popcll(bal & ((1ull << lane) - 1ull));
      if (pos < CAPACITY) { slot[f] = pos; rowmap[e*CAPACITY + pos] = f; }
      else slot[f] = -1;
    }
    base += total;
    __syncthreads();
  }
  if (tid == 0) cnt[e] = (base < CAPACITY) ? base : CAPACITY;
}

// ---------------------------------------------------------------- MoE combine (yb bf16, fp32 accumulate)
__global__ void moe_sum(const __bf16* __restrict__ y, const int* __restrict__ slot,
                        float* __restrict__ h) {
  int t = blockIdx.x, d4 = threadIdx.x;
  float4 acc = ((float4*)(h + (size_t)t*DMODEL))[d4];
#pragma unroll
  for (int kk = 0; kk < TOPK; kk++) {
    int f = t*TOPK + kk;
    if (slot[f] >= 0) {
      bf16x4 yv = *(const bf16x4*)(y + (size_t)f*DMODEL + d4*4);
      acc.x += (float)yv[0]; acc.y += (float)yv[1];
      acc.z += (float)yv[2]; acc.w += (float)yv[3];
    }
  }
  ((float4*)(h + (size_t)t*DMODEL))[d4] = acc;
}

// ---------------------------------------------------------------- final output
__global__ void final_copy(const float* __restrict__ h, float* __restrict__ out) {
  int b = blockIdx.x, tid = threadIdx.x;
  float4 v = ((const float4*)(h + (size_t)b*SEQ*DMODEL))[tid];
  ((float4*)(out + (size_t)b*DMODEL))[tid] = v;
}

// ---------------------------------------------------------------- host
extern "C" void kernel_launch(void* const* d_in, const int* in_sizes, int n_in,
                              void* d_out, int out_size, void* d_ws, size_t ws_size,
                              hipStream_t stream) {
  (void)in_sizes; (void)n_in; (void)out_size; (void)ws_size;
  const float* x         = (const float*)d_in[0];
  const float* conv_w1   = (const float*)d_in[1];
  const float* conv_w2   = (const float*)d_in[2];
  const float* conv_w3   = (const float*)d_in[3];
  const float* bn1_g     = (const float*)d_in[4];
  const float* bn1_b     = (const float*)d_in[5];
  const float* bn2_g     = (const float*)d_in[6];
  const float* bn2_b     = (const float*)d_in[7];
  const float* bn3_g     = (const float*)d_in[8];
  const float* bn3_b     = (const float*)d_in[9];
  const float* proj_w    = (const float*)d_in[10];
  const float* proj_b    = (const float*)d_in[11];
  const float* cls_token = (const float*)d_in[12];
  const float* mask_tok  = (const float*)d_in[13];
  const float* ln1_g     = (const float*)d_in[14];
  const float* ln1_b     = (const float*)d_in[15];
  const float* ln2_g     = (const float*)d_in[16];
  const float* ln2_b     = (const float*)d_in[17];
  const float* wq        = (const float*)d_in[18];
  const float* wk        = (const float*)d_in[19];
  const float* wv        = (const float*)d_in[20];
  const float* wo        = (const float*)d_in[21];
  const float* bq        = (const float*)d_in[22];
  const float* bk        = (const float*)d_in[23];
  const float* bv        = (const float*)d_in[24];
  const float* bo        = (const float*)d_in[25];
  const float* wg        = (const float*)d_in[26];
  const float* bg        = (const float*)d_in[27];
  const float* we1       = (const float*)d_in[28];
  const float* be1       = (const float*)d_in[29];
  const float* we2       = (const float*)d_in[30];
  const float* be2       = (const float*)d_in[31];
  float* out = (float*)d_out;

  char* base = (char*)d_ws;
  const size_t TDB = (size_t)NTOK * DMODEL * 4;         // 16.8 MB
  float*  h    = (float*)(base);                        // 1 TDB
  __bf16* yb   = (__bf16*)(base + 2*TDB);               // 2 TDB (TKF*1024 bf16)
  __bf16* xbf  = (__bf16*)(base + 6*TDB);               // 0.5 TDB
  __bf16* ao   = (__bf16*)(base + 6*TDB + TDB/2);       // 0.5 TDB
  __bf16* qkvb = (__bf16*)(base + 7*TDB);               // 1.5 TDB (NTOK x 3072 bf16)
  __bf16* hid  = (__bf16*)(base + 8*TDB + TDB/2);       // 2 TDB (TKF*1024 bf16)
  char* misc   = base + 11*TDB;
  float* feat  = (float*)misc;                          // NBINTOT*64
  float* gate  = feat + (size_t)NBINTOT*64;
  int* idx     = (int*)(gate + TKF);
  int* slot    = idx + TKF;
  int* rowmap  = slot + TKF;
  int* cnt     = rowmap + NEXP*CAPACITY;
  int* msk     = cnt + 32;
  char* wtb    = base + 12*TDB;                          // weight area
  const size_t MB1 = (size_t)1024*1024;                  // elems per matrix
  __bf16* wqkv = (__bf16*)wtb;                           // [L][3][1024][1024] packed
  __bf16* wto  = wqkv + 12*MB1;                          // 4 mats
  __bf16* wte1 = wto + 4*MB1;                            // 120 mats
  __bf16* wte2 = wte1 + 120*MB1;                         // 120 mats

  // ---- weight convert+transpose to bf16 [n][k]; QKV packed per layer
  transpose_w<<<dim3(256, 4),   256, 0, stream>>>(wq,  wqkv,           3*MB1);
  transpose_w<<<dim3(256, 4),   256, 0, stream>>>(wk,  wqkv + MB1,     3*MB1);
  transpose_w<<<dim3(256, 4),   256, 0, stream>>>(wv,  wqkv + 2*MB1,   3*MB1);
  transpose_w<<<dim3(256, 4),   256, 0, stream>>>(wo,  wto,            MB1);
  transpose_w<<<dim3(256, 120), 256, 0, stream>>>(we1, wte1,           MB1);
  transpose_w<<<dim3(256, 120), 256, 0, stream>>>(we2, wte2,           MB1);

  conv_frontend<<<NBINTOT, 64, 0, stream>>>(x, conv_w1, conv_w2, conv_w3,
      bn1_g, bn1_b, bn2_g, bn2_b, bn3_g, bn3_b, feat, msk);
  embed_kernel<<<dim3(SEQ, BATCH), 256, 0, stream>>>(feat, msk, proj_w, proj_b,
      cls_token, mask_tok, h);

  dim3 gqkv((NTOK + 127)/128, 24);       // 33 x 24  (N=3072, 128-col tiles)
  dim3 gwo((NTOK + 127)/128, 8);         // 33 x 8
  dim3 gmoe(NEXP*9, 8);                  // 270 x 8

  for (int l = 0; l < NLAYER; l++) {
    __bf16* wqkv_l = wqkv + (size_t)l*3*MB1;
    __bf16* wto_l  = wto  + (size_t)l*MB1;
    __bf16* wte1_l = wte1 + (size_t)l*NEXP*MB1;
    __bf16* wte2_l = wte2 + (size_t)l*NEXP*MB1;

    ln_kernel<<<NTOK, 256, 0, stream>>>(h, xbf, ln1_g + (size_t)l*DMODEL, ln1_b + (size_t)l*DMODEL);
    gemm_bf16<0><<<gqkv, 512, 0, stream>>>(xbf, wqkv_l,
        bq + (size_t)l*DMODEL, bk + (size_t)l*DMODEL, bv + (size_t)l*DMODEL,
        qkvb, NTOK, nullptr, nullptr, nullptr);
    attn_mfma<<<dim3(9, BATCH*NHEAD), 256, 0, stream>>>(qkvb, ao);
    gemm_bf16<1><<<gwo, 512, 0, stream>>>(ao, wto_l,
        bo + (size_t)l*DMODEL, nullptr, nullptr, h, NTOK, nullptr, nullptr, nullptr);
    ln_gate<<<NTOK, 256, 0, stream>>>(h, xbf, ln2_g + (size_t)l*DMODEL, ln2_b + (size_t)l*DMODEL,
        wg + (size_t)l*DMODEL*NEXP, bg + (size_t)l*NEXP, idx, gate);
    moe_dispatch<<<NEXP, 256, 0, stream>>>(idx, slot, rowmap, cnt);
    gemm_bf16<2><<<gmoe, 512, 0, stream>>>(xbf, wte1_l,
        be1 + (size_t)l*NEXP*1024, nullptr, nullptr, hid, 0, rowmap, cnt, nullptr);
    gemm_bf16<3><<<gmoe, 512, 0, stream>>>(hid, wte2_l,
        be2 + (size_t)l*NEXP*1024, nullptr, nullptr, yb, 0, rowmap, cnt, gate);
    moe_sum<<<NTOK, 256, 0, stream>>>(yb, slot, h);
  }
  final_copy<<<BATCH, 256, 0, stream>>>(h, out);
}

// Round 13
// 2555.998 us; speedup vs baseline: 1.1586x; 1.0473x over previous
//
#include <hip/hip_runtime.h>
#include <hip/hip_bf16.h>
#include <math.h>

#define BATCH   8
#define NBINS   512
#define BINSZ   10
#define DMODEL  1024
#define NHEAD   8
#define DHEAD   128
#define NLAYER  4
#define NEXP    30
#define TOPK    4
#define SEQ     513            // NBINS + 1
#define NTOK    (BATCH*SEQ)    // 4104
#define NBINTOT (BATCH*NBINS)  // 4096
#define CAPACITY 1152
#define TKF     (NTOK*TOPK)    // 16416
#define QKVLD   3072           // packed qkv row stride

typedef __attribute__((ext_vector_type(8))) __bf16 bf16x8;
typedef __attribute__((ext_vector_type(4))) __bf16 bf16x4;
typedef __attribute__((ext_vector_type(4))) float f32x4;

__device__ __forceinline__ float gelu_f(float x) {
  return 0.5f * x * (1.0f + erff(x * 0.7071067811865475f));
}

__device__ __forceinline__ bf16x8 bf8_zero() {
  int4 z = make_int4(0, 0, 0, 0);
  return __builtin_bit_cast(bf16x8, z);
}

// ---------------------------------------------------------------- weight convert + transpose
__global__ __launch_bounds__(256) void transpose_w(const float* __restrict__ src,
                                                   __bf16* __restrict__ dst, size_t mstride) {
  int mat = blockIdx.y;
  int tile = blockIdx.x;          // 0..255
  int kt = (tile >> 4) * 64;
  int nt = (tile & 15) * 64;
  const float* s = src + (size_t)mat * 1024 * 1024;
  __bf16* d = dst + (size_t)mat * mstride;
  __shared__ float t[64][65];
  int tid = threadIdx.x;
  int r = tid >> 4, c4 = (tid & 15) * 4;
#pragma unroll
  for (int i = 0; i < 4; i++) {
    float4 v = *(const float4*)(s + (size_t)(kt + r + i*16) * 1024 + nt + c4);
    t[r + i*16][c4+0] = v.x; t[r + i*16][c4+1] = v.y;
    t[r + i*16][c4+2] = v.z; t[r + i*16][c4+3] = v.w;
  }
  __syncthreads();
  int r2 = tid >> 2, c2 = (tid & 3) * 16;
  bf16x8 o0, o1;
#pragma unroll
  for (int j = 0; j < 8; j++) { o0[j] = (__bf16)t[c2+j][r2]; o1[j] = (__bf16)t[c2+8+j][r2]; }
  *(bf16x8*)(d + (size_t)(nt + r2) * 1024 + kt + c2)     = o0;
  *(bf16x8*)(d + (size_t)(nt + r2) * 1024 + kt + c2 + 8) = o1;
}

// ---------------------------------------------------------------- conv frontend (named-scalar accs)
#define CSTEP(acc, T, DIL, hr, wA, wB, wC) { \
  float vv_ = (wB) * (hr)[T]; \
  if ((T) >= (DIL)) vv_ = fmaf((wA), (hr)[(T)-(DIL)], vv_); \
  if ((T) + (DIL) <= 9) vv_ = fmaf((wC), (hr)[(T)+(DIL)], vv_); \
  acc += vv_; }

#define CALL10(DIL, hr, wA, wB, wC) \
  CSTEP(t0,0,DIL,hr,wA,wB,wC); CSTEP(t1,1,DIL,hr,wA,wB,wC); \
  CSTEP(t2,2,DIL,hr,wA,wB,wC); CSTEP(t3,3,DIL,hr,wA,wB,wC); \
  CSTEP(t4,4,DIL,hr,wA,wB,wC); CSTEP(t5,5,DIL,hr,wA,wB,wC); \
  CSTEP(t6,6,DIL,hr,wA,wB,wC); CSTEP(t7,7,DIL,hr,wA,wB,wC); \
  CSTEP(t8,8,DIL,hr,wA,wB,wC); CSTEP(t9,9,DIL,hr,wA,wB,wC);

#define ZERO10 float t0=0.f,t1=0.f,t2=0.f,t3=0.f,t4=0.f,t5=0.f,t6=0.f,t7=0.f,t8=0.f,t9=0.f;

#define STORE10(dst, sc, sh) \
  (dst)[0]=gelu_f(t0*(sc)+(sh)); (dst)[1]=gelu_f(t1*(sc)+(sh)); \
  (dst)[2]=gelu_f(t2*(sc)+(sh)); (dst)[3]=gelu_f(t3*(sc)+(sh)); \
  (dst)[4]=gelu_f(t4*(sc)+(sh)); (dst)[5]=gelu_f(t5*(sc)+(sh)); \
  (dst)[6]=gelu_f(t6*(sc)+(sh)); (dst)[7]=gelu_f(t7*(sc)+(sh)); \
  (dst)[8]=gelu_f(t8*(sc)+(sh)); (dst)[9]=gelu_f(t9*(sc)+(sh));

__global__ __launch_bounds__(64) void conv_frontend(const float* __restrict__ x,
                              const float* __restrict__ w1, const float* __restrict__ w2,
                              const float* __restrict__ w3,
                              const float* __restrict__ g1, const float* __restrict__ b1,
                              const float* __restrict__ g2, const float* __restrict__ b2,
                              const float* __restrict__ g3, const float* __restrict__ b3,
                              float* __restrict__ feat, int* __restrict__ msk) {
  const float bnscale = 0.9999950000374997f;   // 1/sqrt(1+1e-5)
  int bin = blockIdx.x;
  int c = threadIdx.x;
  __shared__ float xs[BINSZ];
  __shared__ float h1[16][BINSZ];
  __shared__ float h2[32][BINSZ];
  if (c < BINSZ) xs[c] = x[bin*BINSZ + c];
  if (c == 0) {
    int all = 1;
    for (int t = 0; t < BINSZ; t++) if (x[bin*BINSZ+t] != -100.0f) { all = 0; break; }
    msk[bin] = all;
  }
  __syncthreads();
  if (c < 16) {
    float sc = g1[c]*bnscale, sh = b1[c];
    float wA = w1[c*3], wB = w1[c*3+1], wC = w1[c*3+2];
    const float* hr = &xs[0];
    ZERO10;
    CALL10(1, hr, wA, wB, wC);
    STORE10(&h1[c][0], sc, sh);
  }
  __syncthreads();
  if (c < 32) {
    float sc = g2[c]*bnscale, sh = b2[c];
    ZERO10;
    for (int ci = 0; ci < 16; ci++) {
      const float* w = w2 + (c*16+ci)*3;
      float wA = w[0], wB = w[1], wC = w[2];
      const float* hr = &h1[ci][0];
      CALL10(2, hr, wA, wB, wC);
    }
    STORE10(&h2[c][0], sc, sh);
  }
  __syncthreads();
  {
    float sc = g3[c]*bnscale, sh = b3[c];
    ZERO10;
    for (int ci = 0; ci < 32; ci++) {
      const float* w = w3 + (c*32+ci)*3;
      float wA = w[0], wB = w[1], wC = w[2];
      const float* hr = &h2[ci][0];
      CALL10(4, hr, wA, wB, wC);
    }
    float mean = gelu_f(t0*sc+sh) + gelu_f(t1*sc+sh) + gelu_f(t2*sc+sh)
               + gelu_f(t3*sc+sh) + gelu_f(t4*sc+sh) + gelu_f(t5*sc+sh)
               + gelu_f(t6*sc+sh) + gelu_f(t7*sc+sh) + gelu_f(t8*sc+sh)
               + gelu_f(t9*sc+sh);
    feat[bin*64 + c] = mean * 0.1f;
  }
}

// ---------------------------------------------------------------- embed + PE
__global__ void embed_kernel(const float* __restrict__ feat, const int* __restrict__ msk,
                             const float* __restrict__ proj_w, const float* __restrict__ proj_b,
                             const float* __restrict__ cls_token, const float* __restrict__ mask_token,
                             float* __restrict__ h) {
  int s_ = blockIdx.x;
  int b  = blockIdx.y;
  int tid = threadIdx.x;
  __shared__ __align__(16) float fs[64];
  float out[4];
  if (s_ == 0) {
#pragma unroll
    for (int u = 0; u < 4; u++) out[u] = cls_token[tid*4+u];
  } else {
    int bin = b*NBINS + (s_-1);
    if (tid < 16) ((float4*)fs)[tid] = ((const float4*)(feat + (size_t)bin*64))[tid];
    __syncthreads();
    int m_ = msk[bin];
#pragma unroll
    for (int u = 0; u < 4; u++) {
      int d = tid*4+u;
      float acc = proj_b[d];
      for (int ci = 0; ci < 64; ci++) acc = fmaf(fs[ci], proj_w[ci*DMODEL + d], acc);
      out[u] = m_ ? mask_token[d] : acc;
    }
  }
  const float c0 = -0.008994473019507992f;  // -ln(10000)/1024
#pragma unroll
  for (int u = 0; u < 4; u++) {
    int d = tid*4+u;
    float div = expf(c0 * (float)(d & ~1));
    float ang = (float)s_ * div;
    float pe = (d & 1) ? cosf(ang) : sinf(ang);
    h[((size_t)(b*SEQ + s_))*DMODEL + d] = out[u] + pe;
  }
}

// ---------------------------------------------------------------- layernorm -> bf16 only (ln1)
__global__ void ln_kernel(const float* __restrict__ x, __bf16* __restrict__ outb,
                          const float* __restrict__ g, const float* __restrict__ b) {
  int t = blockIdx.x, tid = threadIdx.x;
  float4 v = ((const float4*)(x + (size_t)t*DMODEL))[tid];
  float s  = v.x+v.y+v.z+v.w;
  float sq = v.x*v.x+v.y*v.y+v.z*v.z+v.w*v.w;
  for (int off = 32; off; off >>= 1) { s += __shfl_down(s, off); sq += __shfl_down(sq, off); }
  __shared__ float ss[4], ssq[4], mv[2];
  int w = tid >> 6, l = tid & 63;
  if (l == 0) { ss[w] = s; ssq[w] = sq; }
  __syncthreads();
  if (tid == 0) {
    float a = 0, c = 0;
    for (int i = 0; i < 4; i++) { a += ss[i]; c += ssq[i]; }
    float mean = a * (1.f/DMODEL);
    float var  = c * (1.f/DMODEL) - mean*mean;
    mv[0] = mean; mv[1] = rsqrtf(var + 1e-5f);
  }
  __syncthreads();
  float mean = mv[0], inv = mv[1];
  float4 gg = ((const float4*)g)[tid];
  float4 bb = ((const float4*)b)[tid];
  float4 o;
  o.x = (v.x-mean)*inv*gg.x + bb.x;
  o.y = (v.y-mean)*inv*gg.y + bb.y;
  o.z = (v.z-mean)*inv*gg.z + bb.z;
  o.w = (v.w-mean)*inv*gg.w + bb.w;
  bf16x4 ob;
  ob[0] = (__bf16)o.x; ob[1] = (__bf16)o.y; ob[2] = (__bf16)o.z; ob[3] = (__bf16)o.w;
  *(bf16x4*)(outb + (size_t)t*DMODEL + tid*4) = ob;
}

// ---------------------------------------------------------------- fused LN2 + MoE gating
__global__ void ln_gate(const float* __restrict__ x, __bf16* __restrict__ outb,
                        const float* __restrict__ g, const float* __restrict__ b,
                        const float* __restrict__ wg, const float* __restrict__ bg,
                        int* __restrict__ idx, float* __restrict__ gate) {
  int t = blockIdx.x, tid = threadIdx.x;
  __shared__ __align__(16) float xs[DMODEL];
  __shared__ float ss[4], ssq[4], mv[2];
  __shared__ float probs[32];
  float4 v = ((const float4*)(x + (size_t)t*DMODEL))[tid];
  float s  = v.x+v.y+v.z+v.w;
  float sq = v.x*v.x+v.y*v.y+v.z*v.z+v.w*v.w;
  for (int off = 32; off; off >>= 1) { s += __shfl_down(s, off); sq += __shfl_down(sq, off); }
  int w = tid >> 6, l = tid & 63;
  if (l == 0) { ss[w] = s; ssq[w] = sq; }
  __syncthreads();
  if (tid == 0) {
    float a = 0, c = 0;
    for (int i = 0; i < 4; i++) { a += ss[i]; c += ssq[i]; }
    float mean = a * (1.f/DMODEL);
    float var  = c * (1.f/DMODEL) - mean*mean;
    mv[0] = mean; mv[1] = rsqrtf(var + 1e-5f);
  }
  __syncthreads();
  float mean = mv[0], inv = mv[1];
  float4 gg = ((const float4*)g)[tid];
  float4 bb = ((const float4*)b)[tid];
  float4 o;
  o.x = (v.x-mean)*inv*gg.x + bb.x;
  o.y = (v.y-mean)*inv*gg.y + bb.y;
  o.z = (v.z-mean)*inv*gg.z + bb.z;
  o.w = (v.w-mean)*inv*gg.w + bb.w;
  bf16x4 ob;
  ob[0] = (__bf16)o.x; ob[1] = (__bf16)o.y; ob[2] = (__bf16)o.z; ob[3] = (__bf16)o.w;
  *(bf16x4*)(outb + (size_t)t*DMODEL + tid*4) = ob;
  ((float4*)xs)[tid] = o;
  __syncthreads();
  int e = tid >> 3, sub = tid & 7;
  if (e < NEXP) {
    float p = 0.f;
    for (int d = sub; d < DMODEL; d += 8) p = fmaf(xs[d], wg[d*NEXP + e], p);
    p += __shfl_down(p, 4, 8);
    p += __shfl_down(p, 2, 8);
    p += __shfl_down(p, 1, 8);
    if (sub == 0) probs[e] = p + bg[e];
  }
  __syncthreads();
  if (tid == 0) {
    float mx = probs[0];
    for (int i = 1; i < NEXP; i++) mx = fmaxf(mx, probs[i]);
    float ssum = 0.f;
    for (int i = 0; i < NEXP; i++) { probs[i] = expf(probs[i]-mx); ssum += probs[i]; }
    float invs = 1.f / ssum;
    float gv[TOPK]; int gi[TOPK]; float gsum = 0.f;
    for (int kk = 0; kk < TOPK; kk++) {
      float best = -1.f; int bi = 0;
      for (int i = 0; i < NEXP; i++) if (probs[i] > best) { best = probs[i]; bi = i; }
      gv[kk] = best * invs; gi[kk] = bi; probs[bi] = -1.f; gsum += gv[kk];
    }
    float ginv = 1.f / gsum;
    for (int kk = 0; kk < TOPK; kk++) { idx[t*TOPK+kk] = gi[kk]; gate[t*TOPK+kk] = gv[kk]*ginv; }
  }
}

// ---------------------------------------------------------------- bf16 MFMA GEMM, 128x128 tile, reg-prefetch (R9 core)
// MODE 0: fused QKV — Wt [3072][1024], C bf16 row-stride 3072, bias per 1024-window
// MODE 1: WO residual — C f32 +=
// MODE 2: MoE ffn1 — gather f>>2, gelu -> hid bf16   (1-D grid, XCD-chunked)
// MODE 3: MoE ffn2 — gather f, gate -> yb bf16       (1-D grid, XCD-chunked)
template<int MODE>
__global__ __launch_bounds__(512) void gemm_bf16(
    const __bf16* __restrict__ A, const __bf16* __restrict__ Wt,
    const float* __restrict__ b0, const float* __restrict__ b1, const float* __restrict__ b2,
    void* __restrict__ C, int M,
    const int* __restrict__ rowmap, const int* __restrict__ cnt,
    const float* __restrict__ gate) {
  int tid = threadIdx.x;
  int rowbase, validrows, e = 0, colbase;
  const __bf16* Wb = Wt;
  if (MODE <= 1) {
    rowbase = blockIdx.x * 128;
    validrows = M - rowbase; if (validrows > 128) validrows = 128;
    colbase = blockIdx.y * 128;
  } else {
    // XCD-aware chunked mapping (bijective: nwg=2160 divisible by 8).
    // logical = e*72 + p*8 + colblock  -> each expert's 72 blocks contiguous,
    // chunk of 270 logical blocks per XCD keeps an expert's weight slice XCD-local.
    int nwg = gridDim.x;                  // 2160
    int logical = (blockIdx.x & 7) * (nwg >> 3) + (blockIdx.x >> 3);
    e = logical / 72;
    int rem = logical - e * 72;
    int p0 = (rem >> 3) * 128;
    colbase = (rem & 7) * 128;
    int ce = cnt[e];
    if (p0 >= ce) return;
    rowbase = p0;
    validrows = ce - p0; if (validrows > 128) validrows = 128;
    Wb = Wt + (size_t)e * 1024 * 1024;
  }

  __shared__ __align__(16) __bf16 As[4][128][8];   // [kgroup][row][8k]
  __shared__ __align__(16) __bf16 Bs[4][128][8];   // [kgroup][col][8k]
  __shared__ int srcrow[128];
  __shared__ int frow[128];

  if (tid < 128) {
    if (MODE <= 1) { srcrow[tid] = rowbase + tid; frow[tid] = rowbase + tid; }
    else if (tid < validrows) {
      int f = rowmap[e*CAPACITY + rowbase + tid];
      frow[tid] = f;
      srcrow[tid] = (MODE == 2) ? (f >> 2) : f;
    } else { frow[tid] = 0; srcrow[tid] = 0; }
  }
  __syncthreads();

  int arow = tid >> 2, ag = tid & 3;            // A: row, k-group (8 bf16 each)
  int wcol = tid & 127, wgp = tid >> 7;         // W: col, k-group
  bool aval = (arow < validrows);
  const __bf16* Ap = A + (size_t)srcrow[arow] * 1024 + ag * 8;
  const __bf16* Wp = Wb + (size_t)(colbase + wcol) * 1024 + wgp * 8;

  int w  = tid >> 6;
  int wr = w & 3, wc = w >> 2;        // wave quadrant: rows wr*32.., cols wc*64..
  int l  = tid & 63;
  int lr = l & 15, lg = l >> 4;

  f32x4 acc[2][4] = {};

  bf16x8 areg = bf8_zero(), breg;
  if (aval) areg = *(const bf16x8*)(Ap);
  breg = *(const bf16x8*)(Wp);

  for (int kt = 0; kt < 1024; kt += 32) {
    __syncthreads();
    *(bf16x8*)&As[ag][arow][0] = areg;
    *(bf16x8*)&Bs[wgp][wcol][0] = breg;
    __syncthreads();

    if (kt + 32 < 1024) {
      if (aval) areg = *(const bf16x8*)(Ap + kt + 32);
      breg = *(const bf16x8*)(Wp + kt + 32);
    }

    bf16x8 af[2], bfr[4];
    af[0] = *(const bf16x8*)&As[lg][wr*32 + lr][0];
    af[1] = *(const bf16x8*)&As[lg][wr*32 + 16 + lr][0];
#pragma unroll
    for (int fj = 0; fj < 4; fj++) bfr[fj] = *(const bf16x8*)&Bs[lg][wc*64 + fj*16 + lr][0];
#pragma unroll
    for (int fi = 0; fi < 2; fi++)
#pragma unroll
      for (int fj = 0; fj < 4; fj++)
        acc[fi][fj] = __builtin_amdgcn_mfma_f32_16x16x32_bf16(af[fi], bfr[fj], acc[fi][fj], 0, 0, 0);
  }

  // epilogue: C/D layout col = l&15, row = (l>>4)*4 + i
  if (MODE == 0) {
    int which = colbase >> 10;              // block-uniform
    int colb0 = colbase & 1023;
    const float* bsel = (which == 0) ? b0 : (which == 1) ? b1 : b2;
#pragma unroll
    for (int fj = 0; fj < 4; fj++) {
      int col = wc*64 + fj*16 + lr;
      float bvv = bsel[colb0 + col];
#pragma unroll
      for (int fi = 0; fi < 2; fi++)
#pragma unroll
        for (int i = 0; i < 4; i++) {
          int r = wr*32 + fi*16 + lg*4 + i;
          if (r >= validrows) continue;
          ((__bf16*)C)[(size_t)(rowbase + r)*QKVLD + colbase + col] = (__bf16)(acc[fi][fj][i] + bvv);
        }
    }
  } else {
    const float* bptr = (MODE >= 2) ? (b0 + (size_t)e * 1024) : b0;
#pragma unroll
    for (int fj = 0; fj < 4; fj++) {
      int col = wc*64 + fj*16 + lr;
      float bvv = bptr[colbase + col];
#pragma unroll
      for (int fi = 0; fi < 2; fi++)
#pragma unroll
        for (int i = 0; i < 4; i++) {
          int r = wr*32 + fi*16 + lg*4 + i;
          if (r >= validrows) continue;
          float val = acc[fi][fj][i] + bvv;
          if (MODE == 1) {
            float* p = (float*)C + (size_t)(rowbase + r)*1024 + colbase + col;
            *p = *p + val;
          } else if (MODE == 2) {
            ((__bf16*)C)[(size_t)frow[r]*1024 + colbase + col] = (__bf16)gelu_f(val);
          } else {
            ((__bf16*)C)[(size_t)frow[r]*1024 + colbase + col] = (__bf16)(gate[frow[r]] * val);
          }
        }
    }
  }
}

// ---------------------------------------------------------------- MFMA flash attention (packed qkv, stride 3072)
__global__ __launch_bounds__(256) void attn_mfma(const __bf16* __restrict__ qkv,
                                                 __bf16* __restrict__ o) {
  int qt = blockIdx.x;
  int bh = blockIdx.y;
  int b = bh >> 3, hh = bh & 7;
  int tid = threadIdx.x;
  int wid = tid >> 6, l = tid & 63;
  int lr = l & 15, lg = l >> 4;

  __shared__ __align__(16) __bf16 Ks[64*128];   // [kk][d] row-major, swizzled
  __shared__ __align__(16) __bf16 Vt[128*64];   // [d][kk] row-major, swizzled

  const float scale = 0.08838834764831845f;  // 1/sqrt(128)

  int qtok = qt*64 + wid*16 + lr;
  int qtokc = qtok < SEQ ? qtok : SEQ-1;
  const __bf16* qrow = qkv + (size_t)(b*SEQ + qtokc)*QKVLD + hh*DHEAD;
  bf16x8 qf[4];
#pragma unroll
  for (int c = 0; c < 4; c++) qf[c] = *(const bf16x8*)(qrow + c*32 + lg*8);

  float mreg = -1e30f, lsum = 0.f;
  f32x4 Oacc[8] = {};

  int krow = tid & 63, kdc = tid >> 6;   // K staging: row, 32-d chunk
  int vd = tid & 127, vkg0 = tid >> 7;   // V staging: d column, kk-group base

  for (int kt = 0; kt < 9; kt++) {
    int kt0 = kt*64;
    __syncthreads();
    {
      int tok = kt0 + krow; if (tok >= SEQ) tok = SEQ-1;
      const __bf16* kr = qkv + (size_t)(b*SEQ + tok)*QKVLD + 1024 + hh*DHEAD + kdc*32;
#pragma unroll
      for (int s2 = 0; s2 < 4; s2++) {
        bf16x8 t = *(const bf16x8*)(kr + s2*8);
        int byte = (krow*256 + (kdc*32 + s2*8)*2) ^ ((krow & 7) << 4);
        *(bf16x8*)((char*)Ks + byte) = t;
      }
    }
    {
#pragma unroll
      for (int it = 0; it < 4; it++) {
        int kkg = vkg0 + it*2;
        bf16x8 t;
#pragma unroll
        for (int j = 0; j < 8; j++) {
          int tok = kt0 + kkg*8 + j; if (tok >= SEQ) tok = SEQ-1;
          t[j] = qkv[(size_t)(b*SEQ + tok)*QKVLD + 2048 + hh*DHEAD + vd];
        }
        int byte = (vd*128 + kkg*16) ^ ((vd & 7) << 4);
        *(bf16x8*)((char*)Vt + byte) = t;
      }
    }
    __syncthreads();

    f32x4 sacc[4] = {};
#pragma unroll
    for (int c = 0; c < 4; c++) {
#pragma unroll
      for (int jb = 0; jb < 4; jb++) {
        int row = jb*16 + lr;
        int byte = (row*256 + (c*32 + lg*8)*2) ^ ((lr & 7) << 4);
        bf16x8 af = *(const bf16x8*)((const char*)Ks + byte);
        sacc[jb] = __builtin_amdgcn_mfma_f32_16x16x32_bf16(af, qf[c], sacc[jb], 0, 0, 0);
      }
    }

    float sv[4][4];
    float mt = -1e30f;
#pragma unroll
    for (int jb = 0; jb < 4; jb++)
#pragma unroll
      for (int i = 0; i < 4; i++) {
        int kkI = kt0 + jb*16 + lg*4 + i;
        float s = sacc[jb][i] * scale;
        if (kkI >= SEQ) s = -1e30f;
        sv[jb][i] = s;
        mt = fmaxf(mt, s);
      }
    mt = fmaxf(mt, __shfl_xor(mt, 16));
    mt = fmaxf(mt, __shfl_xor(mt, 32));
    float mnew = fmaxf(mreg, mt);
    float alpha = expf(mreg - mnew);
    float rs = 0.f;
#pragma unroll
    for (int jb = 0; jb < 4; jb++)
#pragma unroll
      for (int i = 0; i < 4; i++) {
        float p = expf(sv[jb][i] - mnew);
        sv[jb][i] = p; rs += p;
      }
    rs += __shfl_xor(rs, 16);
    rs += __shfl_xor(rs, 32);
    lsum = lsum * alpha + rs;
    mreg = mnew;

    unsigned pk[4][2];
#pragma unroll
    for (int jb = 0; jb < 4; jb++) {
      unsigned short c0 = __builtin_bit_cast(unsigned short, (__bf16)sv[jb][0]);
      unsigned short c1 = __builtin_bit_cast(unsigned short, (__bf16)sv[jb][1]);
      unsigned short c2 = __builtin_bit_cast(unsigned short, (__bf16)sv[jb][2]);
      unsigned short c3 = __builtin_bit_cast(unsigned short, (__bf16)sv[jb][3]);
      pk[jb][0] = ((unsigned)c1 << 16) | c0;
      pk[jb][1] = ((unsigned)c3 << 16) | c2;
    }

    float al0 = __shfl(alpha, lg*4 + 0);
    float al1 = __shfl(alpha, lg*4 + 1);
    float al2 = __shfl(alpha, lg*4 + 2);
    float al3 = __shfl(alpha, lg*4 + 3);
#pragma unroll
    for (int db = 0; db < 8; db++) {
      Oacc[db][0] *= al0; Oacc[db][1] *= al1; Oacc[db][2] *= al2; Oacc[db][3] *= al3;
    }

    int srcA = lr + ((lg & 1) << 5);
    int srcB = srcA + 16;
    bool hiSel = (lg >> 1) != 0;
#pragma unroll
    for (int c = 0; c < 2; c++) {
      int a00 = __shfl((int)pk[2*c][0], srcA);
      int a01 = __shfl((int)pk[2*c][1], srcA);
      int a10 = __shfl((int)pk[2*c+1][0], srcA);
      int a11 = __shfl((int)pk[2*c+1][1], srcA);
      int b00 = __shfl((int)pk[2*c][0], srcB);
      int b01 = __shfl((int)pk[2*c][1], srcB);
      int b10 = __shfl((int)pk[2*c+1][0], srcB);
      int b11 = __shfl((int)pk[2*c+1][1], srcB);
      int4 pa;
      pa.x = hiSel ? a10 : a00;
      pa.y = hiSel ? a11 : a01;
      pa.z = hiSel ? b10 : b00;
      pa.w = hiSel ? b11 : b01;
      bf16x8 paf = __builtin_bit_cast(bf16x8, pa);
#pragma unroll
      for (int db = 0; db < 8; db++) {
        int d = db*16 + lr;
        int byte = (d*128 + (c*32 + lg*8)*2) ^ ((lr & 7) << 4);
        bf16x8 bfv = *(const bf16x8*)((const char*)Vt + byte);
        Oacc[db] = __builtin_amdgcn_mfma_f32_16x16x32_bf16(paf, bfv, Oacc[db], 0, 0, 0);
      }
    }
  }

  float l0 = __shfl(lsum, lg*4 + 0);
  float l1 = __shfl(lsum, lg*4 + 1);
  float l2 = __shfl(lsum, lg*4 + 2);
  float l3 = __shfl(lsum, lg*4 + 3);
  float inv[4] = {1.f/l0, 1.f/l1, 1.f/l2, 1.f/l3};
#pragma unroll
  for (int i = 0; i < 4; i++) {
    int tok = qt*64 + wid*16 + lg*4 + i;
    if (tok < SEQ) {
      __bf16* dst = o + ((size_t)(b*SEQ + tok))*DMODEL + hh*DHEAD + lr;
#pragma unroll
      for (int db = 0; db < 8; db++) dst[db*16] = (__bf16)(Oacc[db][i] * inv[i]);
    }
  }
}

// ---------------------------------------------------------------- MoE dispatch (ballot scan, 1024 threads)
__global__ __launch_bounds__(1024) void moe_dispatch(const int* __restrict__ idx, int* __restrict__ slot,
                             int* __restrict__ rowmap, int* __restrict__ cnt) {
  int e = blockIdx.x, tid = threadIdx.x;
  int lane = tid & 63, wid = tid >> 6;    // 16 waves
  __shared__ int wsum[16];
  int base = 0;
  for (int c0 = 0; c0 < TKF; c0 += 1024) {
    int f = c0 + tid;
    int match = (f < TKF && idx[f] == e) ? 1 : 0;
    unsigned long long bal = __ballot(match);
    if (lane == 0) wsum[wid] = __popcll(bal);
    __syncthreads();
    int prefix = 0, total = 0;
#pragma unroll
    for (int w2 = 0; w2 < 16; w2++) {
      int v = wsum[w2];
      if (w2 < wid) prefix += v;
      total += v;
    }
    if (match) {
      int pos = base + prefix + __popcll(bal & ((1ull << lane) - 1ull));
      if (pos < CAPACITY) { slot[f] = pos; rowmap[e*CAPACITY + pos] = f; }
      else slot[f] = -1;
    }
    base += total;
    __syncthreads();
  }
  if (tid == 0) cnt[e] = (base < CAPACITY) ? base : CAPACITY;
}

// ---------------------------------------------------------------- MoE combine (yb bf16, fp32 accumulate)
__global__ void moe_sum(const __bf16* __restrict__ y, const int* __restrict__ slot,
                        float* __restrict__ h) {
  int t = blockIdx.x, d4 = threadIdx.x;
  float4 acc = ((float4*)(h + (size_t)t*DMODEL))[d4];
#pragma unroll
  for (int kk = 0; kk < TOPK; kk++) {
    int f = t*TOPK + kk;
    if (slot[f] >= 0) {
      bf16x4 yv = *(const bf16x4*)(y + (size_t)f*DMODEL + d4*4);
      acc.x += (float)yv[0]; acc.y += (float)yv[1];
      acc.z += (float)yv[2]; acc.w += (float)yv[3];
    }
  }
  ((float4*)(h + (size_t)t*DMODEL))[d4] = acc;
}

// ---------------------------------------------------------------- final output
__global__ void final_copy(const float* __restrict__ h, float* __restrict__ out) {
  int b = blockIdx.x, tid = threadIdx.x;
  float4 v = ((const float4*)(h + (size_t)b*SEQ*DMODEL))[tid];
  ((float4*)(out + (size_t)b*DMODEL))[tid] = v;
}

// ---------------------------------------------------------------- host
extern "C" void kernel_launch(void* const* d_in, const int* in_sizes, int n_in,
                              void* d_out, int out_size, void* d_ws, size_t ws_size,
                              hipStream_t stream) {
  (void)in_sizes; (void)n_in; (void)out_size; (void)ws_size;
  const float* x         = (const float*)d_in[0];
  const float* conv_w1   = (const float*)d_in[1];
  const float* conv_w2   = (const float*)d_in[2];
  const float* conv_w3   = (const float*)d_in[3];
  const float* bn1_g     = (const float*)d_in[4];
  const float* bn1_b     = (const float*)d_in[5];
  const float* bn2_g     = (const float*)d_in[6];
  const float* bn2_b     = (const float*)d_in[7];
  const float* bn3_g     = (const float*)d_in[8];
  const float* bn3_b     = (const float*)d_in[9];
  const float* proj_w    = (const float*)d_in[10];
  const float* proj_b    = (const float*)d_in[11];
  const float* cls_token = (const float*)d_in[12];
  const float* mask_tok  = (const float*)d_in[13];
  const float* ln1_g     = (const float*)d_in[14];
  const float* ln1_b     = (const float*)d_in[15];
  const float* ln2_g     = (const float*)d_in[16];
  const float* ln2_b     = (const float*)d_in[17];
  const float* wq        = (const float*)d_in[18];
  const float* wk        = (const float*)d_in[19];
  const float* wv        = (const float*)d_in[20];
  const float* wo        = (const float*)d_in[21];
  const float* bq        = (const float*)d_in[22];
  const float* bk        = (const float*)d_in[23];
  const float* bv        = (const float*)d_in[24];
  const float* bo        = (const float*)d_in[25];
  const float* wg        = (const float*)d_in[26];
  const float* bg        = (const float*)d_in[27];
  const float* we1       = (const float*)d_in[28];
  const float* be1       = (const float*)d_in[29];
  const float* we2       = (const float*)d_in[30];
  const float* be2       = (const float*)d_in[31];
  float* out = (float*)d_out;

  char* base = (char*)d_ws;
  const size_t TDB = (size_t)NTOK * DMODEL * 4;         // 16.8 MB
  float*  h    = (float*)(base);                        // 1 TDB
  __bf16* yb   = (__bf16*)(base + 2*TDB);               // 2 TDB (TKF*1024 bf16)
  __bf16* xbf  = (__bf16*)(base + 6*TDB);               // 0.5 TDB
  __bf16* ao   = (__bf16*)(base + 6*TDB + TDB/2);       // 0.5 TDB
  __bf16* qkvb = (__bf16*)(base + 7*TDB);               // 1.5 TDB (NTOK x 3072 bf16)
  __bf16* hid  = (__bf16*)(base + 8*TDB + TDB/2);       // 2 TDB (TKF*1024 bf16)
  char* misc   = base + 11*TDB;
  float* feat  = (float*)misc;                          // NBINTOT*64
  float* gate  = feat + (size_t)NBINTOT*64;
  int* idx     = (int*)(gate + TKF);
  int* slot    = idx + TKF;
  int* rowmap  = slot + TKF;
  int* cnt     = rowmap + NEXP*CAPACITY;
  int* msk     = cnt + 32;
  char* wtb    = base + 12*TDB;                          // weight area
  const size_t MB1 = (size_t)1024*1024;                  // elems per matrix
  __bf16* wqkv = (__bf16*)wtb;                           // [L][3][1024][1024] packed
  __bf16* wto  = wqkv + 12*MB1;                          // 4 mats
  __bf16* wte1 = wto + 4*MB1;                            // 120 mats
  __bf16* wte2 = wte1 + 120*MB1;                         // 120 mats

  // ---- weight convert+transpose to bf16 [n][k]; QKV packed per layer
  transpose_w<<<dim3(256, 4),   256, 0, stream>>>(wq,  wqkv,           3*MB1);
  transpose_w<<<dim3(256, 4),   256, 0, stream>>>(wk,  wqkv + MB1,     3*MB1);
  transpose_w<<<dim3(256, 4),   256, 0, stream>>>(wv,  wqkv + 2*MB1,   3*MB1);
  transpose_w<<<dim3(256, 4),   256, 0, stream>>>(wo,  wto,            MB1);
  transpose_w<<<dim3(256, 120), 256, 0, stream>>>(we1, wte1,           MB1);
  transpose_w<<<dim3(256, 120), 256, 0, stream>>>(we2, wte2,           MB1);

  conv_frontend<<<NBINTOT, 64, 0, stream>>>(x, conv_w1, conv_w2, conv_w3,
      bn1_g, bn1_b, bn2_g, bn2_b, bn3_g, bn3_b, feat, msk);
  embed_kernel<<<dim3(SEQ, BATCH), 256, 0, stream>>>(feat, msk, proj_w, proj_b,
      cls_token, mask_tok, h);

  dim3 gqkv((NTOK + 127)/128, 24);       // 33 x 24  (N=3072, 128-col tiles)
  dim3 gwo((NTOK + 127)/128, 8);         // 33 x 8
  int  gmoe = NEXP * 72;                 // 2160 (1-D, XCD-chunked in-kernel)

  for (int l = 0; l < NLAYER; l++) {
    __bf16* wqkv_l = wqkv + (size_t)l*3*MB1;
    __bf16* wto_l  = wto  + (size_t)l*MB1;
    __bf16* wte1_l = wte1 + (size_t)l*NEXP*MB1;
    __bf16* wte2_l = wte2 + (size_t)l*NEXP*MB1;

    ln_kernel<<<NTOK, 256, 0, stream>>>(h, xbf, ln1_g + (size_t)l*DMODEL, ln1_b + (size_t)l*DMODEL);
    gemm_bf16<0><<<gqkv, 512, 0, stream>>>(xbf, wqkv_l,
        bq + (size_t)l*DMODEL, bk + (size_t)l*DMODEL, bv + (size_t)l*DMODEL,
        qkvb, NTOK, nullptr, nullptr, nullptr);
    attn_mfma<<<dim3(9, BATCH*NHEAD), 256, 0, stream>>>(qkvb, ao);
    gemm_bf16<1><<<gwo, 512, 0, stream>>>(ao, wto_l,
        bo + (size_t)l*DMODEL, nullptr, nullptr, h, NTOK, nullptr, nullptr, nullptr);
    ln_gate<<<NTOK, 256, 0, stream>>>(h, xbf, ln2_g + (size_t)l*DMODEL, ln2_b + (size_t)l*DMODEL,
        wg + (size_t)l*DMODEL*NEXP, bg + (size_t)l*NEXP, idx, gate);
    moe_dispatch<<<NEXP, 1024, 0, stream>>>(idx, slot, rowmap, cnt);
    gemm_bf16<2><<<gmoe, 512, 0, stream>>>(xbf, wte1_l,
        be1 + (size_t)l*NEXP*1024, nullptr, nullptr, hid, 0, rowmap, cnt, nullptr);
    gemm_bf16<3><<<gmoe, 512, 0, stream>>>(hid, wte2_l,
        be2 + (size_t)l*NEXP*1024, nullptr, nullptr, yb, 0, rowmap, cnt, gate);
    moe_sum<<<NTOK, 256, 0, stream>>>(yb, slot, h);
  }
  final_copy<<<BATCH, 256, 0, stream>>>(h, out);
}

// Round 14
// 2541.306 us; speedup vs baseline: 1.1653x; 1.0058x over previous
//
#include <hip/hip_runtime.h>
#include <hip/hip_bf16.h>
#include <math.h>

#define BATCH   8
#define NBINS   512
#define BINSZ   10
#define DMODEL  1024
#define NHEAD   8
#define DHEAD   128
#define NLAYER  4
#define NEXP    30
#define TOPK    4
#define SEQ     513            // NBINS + 1
#define NTOK    (BATCH*SEQ)    // 4104
#define NBINTOT (BATCH*NBINS)  // 4096
#define CAPACITY 1152
#define TKF     (NTOK*TOPK)    // 16416
#define QKVLD   3072           // packed qkv row stride
#define RTILES  33             // ceil(NTOK/128)

typedef __attribute__((ext_vector_type(8))) __bf16 bf16x8;
typedef __attribute__((ext_vector_type(4))) __bf16 bf16x4;
typedef __attribute__((ext_vector_type(4))) float f32x4;

__device__ __forceinline__ float gelu_f(float x) {
  return 0.5f * x * (1.0f + erff(x * 0.7071067811865475f));
}

__device__ __forceinline__ bf16x8 bf8_zero() {
  int4 z = make_int4(0, 0, 0, 0);
  return __builtin_bit_cast(bf16x8, z);
}

// bijective XCD-chunked remap: nwg must be divisible by 8.
__device__ __forceinline__ int xcd_logical(int bid, int nwg) {
  return (bid & 7) * (nwg >> 3) + (bid >> 3);
}

// ---------------------------------------------------------------- weight convert + transpose
__global__ __launch_bounds__(256) void transpose_w(const float* __restrict__ src,
                                                   __bf16* __restrict__ dst, size_t mstride) {
  int mat = blockIdx.y;
  int tile = blockIdx.x;          // 0..255
  int kt = (tile >> 4) * 64;
  int nt = (tile & 15) * 64;
  const float* s = src + (size_t)mat * 1024 * 1024;
  __bf16* d = dst + (size_t)mat * mstride;
  __shared__ float t[64][65];
  int tid = threadIdx.x;
  int r = tid >> 4, c4 = (tid & 15) * 4;
#pragma unroll
  for (int i = 0; i < 4; i++) {
    float4 v = *(const float4*)(s + (size_t)(kt + r + i*16) * 1024 + nt + c4);
    t[r + i*16][c4+0] = v.x; t[r + i*16][c4+1] = v.y;
    t[r + i*16][c4+2] = v.z; t[r + i*16][c4+3] = v.w;
  }
  __syncthreads();
  int r2 = tid >> 2, c2 = (tid & 3) * 16;
  bf16x8 o0, o1;
#pragma unroll
  for (int j = 0; j < 8; j++) { o0[j] = (__bf16)t[c2+j][r2]; o1[j] = (__bf16)t[c2+8+j][r2]; }
  *(bf16x8*)(d + (size_t)(nt + r2) * 1024 + kt + c2)     = o0;
  *(bf16x8*)(d + (size_t)(nt + r2) * 1024 + kt + c2 + 8) = o1;
}

// ---------------------------------------------------------------- conv frontend (named-scalar accs)
#define CSTEP(acc, T, DIL, hr, wA, wB, wC) { \
  float vv_ = (wB) * (hr)[T]; \
  if ((T) >= (DIL)) vv_ = fmaf((wA), (hr)[(T)-(DIL)], vv_); \
  if ((T) + (DIL) <= 9) vv_ = fmaf((wC), (hr)[(T)+(DIL)], vv_); \
  acc += vv_; }

#define CALL10(DIL, hr, wA, wB, wC) \
  CSTEP(t0,0,DIL,hr,wA,wB,wC); CSTEP(t1,1,DIL,hr,wA,wB,wC); \
  CSTEP(t2,2,DIL,hr,wA,wB,wC); CSTEP(t3,3,DIL,hr,wA,wB,wC); \
  CSTEP(t4,4,DIL,hr,wA,wB,wC); CSTEP(t5,5,DIL,hr,wA,wB,wC); \
  CSTEP(t6,6,DIL,hr,wA,wB,wC); CSTEP(t7,7,DIL,hr,wA,wB,wC); \
  CSTEP(t8,8,DIL,hr,wA,wB,wC); CSTEP(t9,9,DIL,hr,wA,wB,wC);

#define ZERO10 float t0=0.f,t1=0.f,t2=0.f,t3=0.f,t4=0.f,t5=0.f,t6=0.f,t7=0.f,t8=0.f,t9=0.f;

#define STORE10(dst, sc, sh) \
  (dst)[0]=gelu_f(t0*(sc)+(sh)); (dst)[1]=gelu_f(t1*(sc)+(sh)); \
  (dst)[2]=gelu_f(t2*(sc)+(sh)); (dst)[3]=gelu_f(t3*(sc)+(sh)); \
  (dst)[4]=gelu_f(t4*(sc)+(sh)); (dst)[5]=gelu_f(t5*(sc)+(sh)); \
  (dst)[6]=gelu_f(t6*(sc)+(sh)); (dst)[7]=gelu_f(t7*(sc)+(sh)); \
  (dst)[8]=gelu_f(t8*(sc)+(sh)); (dst)[9]=gelu_f(t9*(sc)+(sh));

__global__ __launch_bounds__(64) void conv_frontend(const float* __restrict__ x,
                              const float* __restrict__ w1, const float* __restrict__ w2,
                              const float* __restrict__ w3,
                              const float* __restrict__ g1, const float* __restrict__ b1,
                              const float* __restrict__ g2, const float* __restrict__ b2,
                              const float* __restrict__ g3, const float* __restrict__ b3,
                              float* __restrict__ feat, int* __restrict__ msk) {
  const float bnscale = 0.9999950000374997f;   // 1/sqrt(1+1e-5)
  int bin = blockIdx.x;
  int c = threadIdx.x;
  __shared__ float xs[BINSZ];
  __shared__ float h1[16][BINSZ];
  __shared__ float h2[32][BINSZ];
  if (c < BINSZ) xs[c] = x[bin*BINSZ + c];
  if (c == 0) {
    int all = 1;
    for (int t = 0; t < BINSZ; t++) if (x[bin*BINSZ+t] != -100.0f) { all = 0; break; }
    msk[bin] = all;
  }
  __syncthreads();
  if (c < 16) {
    float sc = g1[c]*bnscale, sh = b1[c];
    float wA = w1[c*3], wB = w1[c*3+1], wC = w1[c*3+2];
    const float* hr = &xs[0];
    ZERO10;
    CALL10(1, hr, wA, wB, wC);
    STORE10(&h1[c][0], sc, sh);
  }
  __syncthreads();
  if (c < 32) {
    float sc = g2[c]*bnscale, sh = b2[c];
    ZERO10;
    for (int ci = 0; ci < 16; ci++) {
      const float* w = w2 + (c*16+ci)*3;
      float wA = w[0], wB = w[1], wC = w[2];
      const float* hr = &h1[ci][0];
      CALL10(2, hr, wA, wB, wC);
    }
    STORE10(&h2[c][0], sc, sh);
  }
  __syncthreads();
  {
    float sc = g3[c]*bnscale, sh = b3[c];
    ZERO10;
    for (int ci = 0; ci < 32; ci++) {
      const float* w = w3 + (c*32+ci)*3;
      float wA = w[0], wB = w[1], wC = w[2];
      const float* hr = &h2[ci][0];
      CALL10(4, hr, wA, wB, wC);
    }
    float mean = gelu_f(t0*sc+sh) + gelu_f(t1*sc+sh) + gelu_f(t2*sc+sh)
               + gelu_f(t3*sc+sh) + gelu_f(t4*sc+sh) + gelu_f(t5*sc+sh)
               + gelu_f(t6*sc+sh) + gelu_f(t7*sc+sh) + gelu_f(t8*sc+sh)
               + gelu_f(t9*sc+sh);
    feat[bin*64 + c] = mean * 0.1f;
  }
}

// ---------------------------------------------------------------- embed + PE
__global__ void embed_kernel(const float* __restrict__ feat, const int* __restrict__ msk,
                             const float* __restrict__ proj_w, const float* __restrict__ proj_b,
                             const float* __restrict__ cls_token, const float* __restrict__ mask_token,
                             float* __restrict__ h) {
  int s_ = blockIdx.x;
  int b  = blockIdx.y;
  int tid = threadIdx.x;
  __shared__ __align__(16) float fs[64];
  float out[4];
  if (s_ == 0) {
#pragma unroll
    for (int u = 0; u < 4; u++) out[u] = cls_token[tid*4+u];
  } else {
    int bin = b*NBINS + (s_-1);
    if (tid < 16) ((float4*)fs)[tid] = ((const float4*)(feat + (size_t)bin*64))[tid];
    __syncthreads();
    int m_ = msk[bin];
#pragma unroll
    for (int u = 0; u < 4; u++) {
      int d = tid*4+u;
      float acc = proj_b[d];
      for (int ci = 0; ci < 64; ci++) acc = fmaf(fs[ci], proj_w[ci*DMODEL + d], acc);
      out[u] = m_ ? mask_token[d] : acc;
    }
  }
  const float c0 = -0.008994473019507992f;  // -ln(10000)/1024
#pragma unroll
  for (int u = 0; u < 4; u++) {
    int d = tid*4+u;
    float div = expf(c0 * (float)(d & ~1));
    float ang = (float)s_ * div;
    float pe = (d & 1) ? cosf(ang) : sinf(ang);
    h[((size_t)(b*SEQ + s_))*DMODEL + d] = out[u] + pe;
  }
}

// ---------------------------------------------------------------- layernorm -> bf16 only (ln1)
__global__ void ln_kernel(const float* __restrict__ x, __bf16* __restrict__ outb,
                          const float* __restrict__ g, const float* __restrict__ b) {
  int t = blockIdx.x, tid = threadIdx.x;
  float4 v = ((const float4*)(x + (size_t)t*DMODEL))[tid];
  float s  = v.x+v.y+v.z+v.w;
  float sq = v.x*v.x+v.y*v.y+v.z*v.z+v.w*v.w;
  for (int off = 32; off; off >>= 1) { s += __shfl_down(s, off); sq += __shfl_down(sq, off); }
  __shared__ float ss[4], ssq[4], mv[2];
  int w = tid >> 6, l = tid & 63;
  if (l == 0) { ss[w] = s; ssq[w] = sq; }
  __syncthreads();
  if (tid == 0) {
    float a = 0, c = 0;
    for (int i = 0; i < 4; i++) { a += ss[i]; c += ssq[i]; }
    float mean = a * (1.f/DMODEL);
    float var  = c * (1.f/DMODEL) - mean*mean;
    mv[0] = mean; mv[1] = rsqrtf(var + 1e-5f);
  }
  __syncthreads();
  float mean = mv[0], inv = mv[1];
  float4 gg = ((const float4*)g)[tid];
  float4 bb = ((const float4*)b)[tid];
  float4 o;
  o.x = (v.x-mean)*inv*gg.x + bb.x;
  o.y = (v.y-mean)*inv*gg.y + bb.y;
  o.z = (v.z-mean)*inv*gg.z + bb.z;
  o.w = (v.w-mean)*inv*gg.w + bb.w;
  bf16x4 ob;
  ob[0] = (__bf16)o.x; ob[1] = (__bf16)o.y; ob[2] = (__bf16)o.z; ob[3] = (__bf16)o.w;
  *(bf16x4*)(outb + (size_t)t*DMODEL + tid*4) = ob;
}

// ---------------------------------------------------------------- fused LN2 + MoE gating
__global__ void ln_gate(const float* __restrict__ x, __bf16* __restrict__ outb,
                        const float* __restrict__ g, const float* __restrict__ b,
                        const float* __restrict__ wg, const float* __restrict__ bg,
                        int* __restrict__ idx, float* __restrict__ gate) {
  int t = blockIdx.x, tid = threadIdx.x;
  __shared__ __align__(16) float xs[DMODEL];
  __shared__ float ss[4], ssq[4], mv[2];
  __shared__ float probs[32];
  float4 v = ((const float4*)(x + (size_t)t*DMODEL))[tid];
  float s  = v.x+v.y+v.z+v.w;
  float sq = v.x*v.x+v.y*v.y+v.z*v.z+v.w*v.w;
  for (int off = 32; off; off >>= 1) { s += __shfl_down(s, off); sq += __shfl_down(sq, off); }
  int w = tid >> 6, l = tid & 63;
  if (l == 0) { ss[w] = s; ssq[w] = sq; }
  __syncthreads();
  if (tid == 0) {
    float a = 0, c = 0;
    for (int i = 0; i < 4; i++) { a += ss[i]; c += ssq[i]; }
    float mean = a * (1.f/DMODEL);
    float var  = c * (1.f/DMODEL) - mean*mean;
    mv[0] = mean; mv[1] = rsqrtf(var + 1e-5f);
  }
  __syncthreads();
  float mean = mv[0], inv = mv[1];
  float4 gg = ((const float4*)g)[tid];
  float4 bb = ((const float4*)b)[tid];
  float4 o;
  o.x = (v.x-mean)*inv*gg.x + bb.x;
  o.y = (v.y-mean)*inv*gg.y + bb.y;
  o.z = (v.z-mean)*inv*gg.z + bb.z;
  o.w = (v.w-mean)*inv*gg.w + bb.w;
  bf16x4 ob;
  ob[0] = (__bf16)o.x; ob[1] = (__bf16)o.y; ob[2] = (__bf16)o.z; ob[3] = (__bf16)o.w;
  *(bf16x4*)(outb + (size_t)t*DMODEL + tid*4) = ob;
  ((float4*)xs)[tid] = o;
  __syncthreads();
  int e = tid >> 3, sub = tid & 7;
  if (e < NEXP) {
    float p = 0.f;
    for (int d = sub; d < DMODEL; d += 8) p = fmaf(xs[d], wg[d*NEXP + e], p);
    p += __shfl_down(p, 4, 8);
    p += __shfl_down(p, 2, 8);
    p += __shfl_down(p, 1, 8);
    if (sub == 0) probs[e] = p + bg[e];
  }
  __syncthreads();
  if (tid == 0) {
    float mx = probs[0];
    for (int i = 1; i < NEXP; i++) mx = fmaxf(mx, probs[i]);
    float ssum = 0.f;
    for (int i = 0; i < NEXP; i++) { probs[i] = expf(probs[i]-mx); ssum += probs[i]; }
    float invs = 1.f / ssum;
    float gv[TOPK]; int gi[TOPK]; float gsum = 0.f;
    for (int kk = 0; kk < TOPK; kk++) {
      float best = -1.f; int bi = 0;
      for (int i = 0; i < NEXP; i++) if (probs[i] > best) { best = probs[i]; bi = i; }
      gv[kk] = best * invs; gi[kk] = bi; probs[bi] = -1.f; gsum += gv[kk];
    }
    float ginv = 1.f / gsum;
    for (int kk = 0; kk < TOPK; kk++) { idx[t*TOPK+kk] = gi[kk]; gate[t*TOPK+kk] = gv[kk]*ginv; }
  }
}

// ---------------------------------------------------------------- bf16 MFMA GEMM, 128x128 tile, reg-prefetch
// All modes use 1-D grids with bijective XCD-chunked remap (col-sharing blocks XCD-local).
// MODE 0: fused QKV — nwg = RTILES*24; logical = ctile*RTILES + rtile
// MODE 1: WO residual — nwg = RTILES*8
// MODE 2: MoE ffn1 — nwg = NEXP*72; logical = e*72 + p*8 + colblock
// MODE 3: MoE ffn2 — same mapping as 2
template<int MODE>
__global__ __launch_bounds__(512) void gemm_bf16(
    const __bf16* __restrict__ A, const __bf16* __restrict__ Wt,
    const float* __restrict__ b0, const float* __restrict__ b1, const float* __restrict__ b2,
    void* __restrict__ C, int M,
    const int* __restrict__ rowmap, const int* __restrict__ cnt,
    const float* __restrict__ gate) {
  int tid = threadIdx.x;
  int rowbase, validrows, e = 0, colbase;
  const __bf16* Wb = Wt;
  if (MODE <= 1) {
    int logical = xcd_logical(blockIdx.x, gridDim.x);
    int ctile = logical / RTILES;
    int rtile = logical - ctile * RTILES;
    rowbase = rtile * 128;
    validrows = M - rowbase; if (validrows > 128) validrows = 128;
    colbase = ctile * 128;
  } else {
    int logical = xcd_logical(blockIdx.x, gridDim.x);   // nwg = 2160
    e = logical / 72;
    int rem = logical - e * 72;
    int p0 = (rem >> 3) * 128;
    colbase = (rem & 7) * 128;
    int ce = cnt[e];
    if (p0 >= ce) return;
    rowbase = p0;
    validrows = ce - p0; if (validrows > 128) validrows = 128;
    Wb = Wt + (size_t)e * 1024 * 1024;
  }

  __shared__ __align__(16) __bf16 As[4][128][8];   // [kgroup][row][8k]
  __shared__ __align__(16) __bf16 Bs[4][128][8];   // [kgroup][col][8k]
  __shared__ int srcrow[128];
  __shared__ int frow[128];

  if (tid < 128) {
    if (MODE <= 1) { srcrow[tid] = rowbase + tid; frow[tid] = rowbase + tid; }
    else if (tid < validrows) {
      int f = rowmap[e*CAPACITY + rowbase + tid];
      frow[tid] = f;
      srcrow[tid] = (MODE == 2) ? (f >> 2) : f;
    } else { frow[tid] = 0; srcrow[tid] = 0; }
  }
  __syncthreads();

  int arow = tid >> 2, ag = tid & 3;            // A: row, k-group (8 bf16 each)
  int wcol = tid & 127, wgp = tid >> 7;         // W: col, k-group
  bool aval = (arow < validrows);
  const __bf16* Ap = A + (size_t)srcrow[arow] * 1024 + ag * 8;
  const __bf16* Wp = Wb + (size_t)(colbase + wcol) * 1024 + wgp * 8;

  int w  = tid >> 6;
  int wr = w & 3, wc = w >> 2;        // wave quadrant: rows wr*32.., cols wc*64..
  int l  = tid & 63;
  int lr = l & 15, lg = l >> 4;

  f32x4 acc[2][4] = {};

  bf16x8 areg = bf8_zero(), breg;
  if (aval) areg = *(const bf16x8*)(Ap);
  breg = *(const bf16x8*)(Wp);

  for (int kt = 0; kt < 1024; kt += 32) {
    __syncthreads();
    *(bf16x8*)&As[ag][arow][0] = areg;
    *(bf16x8*)&Bs[wgp][wcol][0] = breg;
    __syncthreads();

    if (kt + 32 < 1024) {
      if (aval) areg = *(const bf16x8*)(Ap + kt + 32);
      breg = *(const bf16x8*)(Wp + kt + 32);
    }

    bf16x8 af[2], bfr[4];
    af[0] = *(const bf16x8*)&As[lg][wr*32 + lr][0];
    af[1] = *(const bf16x8*)&As[lg][wr*32 + 16 + lr][0];
#pragma unroll
    for (int fj = 0; fj < 4; fj++) bfr[fj] = *(const bf16x8*)&Bs[lg][wc*64 + fj*16 + lr][0];
#pragma unroll
    for (int fi = 0; fi < 2; fi++)
#pragma unroll
      for (int fj = 0; fj < 4; fj++)
        acc[fi][fj] = __builtin_amdgcn_mfma_f32_16x16x32_bf16(af[fi], bfr[fj], acc[fi][fj], 0, 0, 0);
  }

  // epilogue: C/D layout col = l&15, row = (l>>4)*4 + i
  if (MODE == 0) {
    int which = colbase >> 10;              // block-uniform
    int colb0 = colbase & 1023;
    const float* bsel = (which == 0) ? b0 : (which == 1) ? b1 : b2;
#pragma unroll
    for (int fj = 0; fj < 4; fj++) {
      int col = wc*64 + fj*16 + lr;
      float bvv = bsel[colb0 + col];
#pragma unroll
      for (int fi = 0; fi < 2; fi++)
#pragma unroll
        for (int i = 0; i < 4; i++) {
          int r = wr*32 + fi*16 + lg*4 + i;
          if (r >= validrows) continue;
          ((__bf16*)C)[(size_t)(rowbase + r)*QKVLD + colbase + col] = (__bf16)(acc[fi][fj][i] + bvv);
        }
    }
  } else {
    const float* bptr = (MODE >= 2) ? (b0 + (size_t)e * 1024) : b0;
#pragma unroll
    for (int fj = 0; fj < 4; fj++) {
      int col = wc*64 + fj*16 + lr;
      float bvv = bptr[colbase + col];
#pragma unroll
      for (int fi = 0; fi < 2; fi++)
#pragma unroll
        for (int i = 0; i < 4; i++) {
          int r = wr*32 + fi*16 + lg*4 + i;
          if (r >= validrows) continue;
          float val = acc[fi][fj][i] + bvv;
          if (MODE == 1) {
            float* p = (float*)C + (size_t)(rowbase + r)*1024 + colbase + col;
            *p = *p + val;
          } else if (MODE == 2) {
            ((__bf16*)C)[(size_t)frow[r]*1024 + colbase + col] = (__bf16)gelu_f(val);
          } else {
            ((__bf16*)C)[(size_t)frow[r]*1024 + colbase + col] = (__bf16)(gate[frow[r]] * val);
          }
        }
    }
  }
}

// ---------------------------------------------------------------- MFMA flash attention (packed qkv, stride 3072)
// 1-D grid 576, XCD-chunked: logical = bh*9 + qt -> one (b,h)'s 9 q-tiles XCD-local (shared K/V).
__global__ __launch_bounds__(256) void attn_mfma(const __bf16* __restrict__ qkv,
                                                 __bf16* __restrict__ o) {
  int logical = xcd_logical(blockIdx.x, gridDim.x);   // nwg = 576
  int bh = logical / 9;
  int qt = logical - bh * 9;
  int b = bh >> 3, hh = bh & 7;
  int tid = threadIdx.x;
  int wid = tid >> 6, l = tid & 63;
  int lr = l & 15, lg = l >> 4;

  __shared__ __align__(16) __bf16 Ks[64*128];   // [kk][d] row-major, swizzled
  __shared__ __align__(16) __bf16 Vt[128*64];   // [d][kk] row-major, swizzled

  const float scale = 0.08838834764831845f;  // 1/sqrt(128)

  int qtok = qt*64 + wid*16 + lr;
  int qtokc = qtok < SEQ ? qtok : SEQ-1;
  const __bf16* qrow = qkv + (size_t)(b*SEQ + qtokc)*QKVLD + hh*DHEAD;
  bf16x8 qf[4];
#pragma unroll
  for (int c = 0; c < 4; c++) qf[c] = *(const bf16x8*)(qrow + c*32 + lg*8);

  float mreg = -1e30f, lsum = 0.f;
  f32x4 Oacc[8] = {};

  int krow = tid & 63, kdc = tid >> 6;   // K staging: row, 32-d chunk
  int vd = tid & 127, vkg0 = tid >> 7;   // V staging: d column, kk-group base

  for (int kt = 0; kt < 9; kt++) {
    int kt0 = kt*64;
    __syncthreads();
    {
      int tok = kt0 + krow; if (tok >= SEQ) tok = SEQ-1;
      const __bf16* kr = qkv + (size_t)(b*SEQ + tok)*QKVLD + 1024 + hh*DHEAD + kdc*32;
#pragma unroll
      for (int s2 = 0; s2 < 4; s2++) {
        bf16x8 t = *(const bf16x8*)(kr + s2*8);
        int byte = (krow*256 + (kdc*32 + s2*8)*2) ^ ((krow & 7) << 4);
        *(bf16x8*)((char*)Ks + byte) = t;
      }
    }
    {
#pragma unroll
      for (int it = 0; it < 4; it++) {
        int kkg = vkg0 + it*2;
        bf16x8 t;
#pragma unroll
        for (int j = 0; j < 8; j++) {
          int tok = kt0 + kkg*8 + j; if (tok >= SEQ) tok = SEQ-1;
          t[j] = qkv[(size_t)(b*SEQ + tok)*QKVLD + 2048 + hh*DHEAD + vd];
        }
        int byte = (vd*128 + kkg*16) ^ ((vd & 7) << 4);
        *(bf16x8*)((char*)Vt + byte) = t;
      }
    }
    __syncthreads();

    f32x4 sacc[4] = {};
#pragma unroll
    for (int c = 0; c < 4; c++) {
#pragma unroll
      for (int jb = 0; jb < 4; jb++) {
        int row = jb*16 + lr;
        int byte = (row*256 + (c*32 + lg*8)*2) ^ ((lr & 7) << 4);
        bf16x8 af = *(const bf16x8*)((const char*)Ks + byte);
        sacc[jb] = __builtin_amdgcn_mfma_f32_16x16x32_bf16(af, qf[c], sacc[jb], 0, 0, 0);
      }
    }

    float sv[4][4];
    float mt = -1e30f;
#pragma unroll
    for (int jb = 0; jb < 4; jb++)
#pragma unroll
      for (int i = 0; i < 4; i++) {
        int kkI = kt0 + jb*16 + lg*4 + i;
        float s = sacc[jb][i] * scale;
        if (kkI >= SEQ) s = -1e30f;
        sv[jb][i] = s;
        mt = fmaxf(mt, s);
      }
    mt = fmaxf(mt, __shfl_xor(mt, 16));
    mt = fmaxf(mt, __shfl_xor(mt, 32));
    float mnew = fmaxf(mreg, mt);
    float alpha = expf(mreg - mnew);
    float rs = 0.f;
#pragma unroll
    for (int jb = 0; jb < 4; jb++)
#pragma unroll
      for (int i = 0; i < 4; i++) {
        float p = expf(sv[jb][i] - mnew);
        sv[jb][i] = p; rs += p;
      }
    rs += __shfl_xor(rs, 16);
    rs += __shfl_xor(rs, 32);
    lsum = lsum * alpha + rs;
    mreg = mnew;

    unsigned pk[4][2];
#pragma unroll
    for (int jb = 0; jb < 4; jb++) {
      unsigned short c0 = __builtin_bit_cast(unsigned short, (__bf16)sv[jb][0]);
      unsigned short c1 = __builtin_bit_cast(unsigned short, (__bf16)sv[jb][1]);
      unsigned short c2 = __builtin_bit_cast(unsigned short, (__bf16)sv[jb][2]);
      unsigned short c3 = __builtin_bit_cast(unsigned short, (__bf16)sv[jb][3]);
      pk[jb][0] = ((unsigned)c1 << 16) | c0;
      pk[jb][1] = ((unsigned)c3 << 16) | c2;
    }

    float al0 = __shfl(alpha, lg*4 + 0);
    float al1 = __shfl(alpha, lg*4 + 1);
    float al2 = __shfl(alpha, lg*4 + 2);
    float al3 = __shfl(alpha, lg*4 + 3);
#pragma unroll
    for (int db = 0; db < 8; db++) {
      Oacc[db][0] *= al0; Oacc[db][1] *= al1; Oacc[db][2] *= al2; Oacc[db][3] *= al3;
    }

    int srcA = lr + ((lg & 1) << 5);
    int srcB = srcA + 16;
    bool hiSel = (lg >> 1) != 0;
#pragma unroll
    for (int c = 0; c < 2; c++) {
      int a00 = __shfl((int)pk[2*c][0], srcA);
      int a01 = __shfl((int)pk[2*c][1], srcA);
      int a10 = __shfl((int)pk[2*c+1][0], srcA);
      int a11 = __shfl((int)pk[2*c+1][1], srcA);
      int b00 = __shfl((int)pk[2*c][0], srcB);
      int b01 = __shfl((int)pk[2*c][1], srcB);
      int b10 = __shfl((int)pk[2*c+1][0], srcB);
      int b11 = __shfl((int)pk[2*c+1][1], srcB);
      int4 pa;
      pa.x = hiSel ? a10 : a00;
      pa.y = hiSel ? a11 : a01;
      pa.z = hiSel ? b10 : b00;
      pa.w = hiSel ? b11 : b01;
      bf16x8 paf = __builtin_bit_cast(bf16x8, pa);
#pragma unroll
      for (int db = 0; db < 8; db++) {
        int d = db*16 + lr;
        int byte = (d*128 + (c*32 + lg*8)*2) ^ ((lr & 7) << 4);
        bf16x8 bfv = *(const bf16x8*)((const char*)Vt + byte);
        Oacc[db] = __builtin_amdgcn_mfma_f32_16x16x32_bf16(paf, bfv, Oacc[db], 0, 0, 0);
      }
    }
  }

  float l0 = __shfl(lsum, lg*4 + 0);
  float l1 = __shfl(lsum, lg*4 + 1);
  float l2 = __shfl(lsum, lg*4 + 2);
  float l3 = __shfl(lsum, lg*4 + 3);
  float inv[4] = {1.f/l0, 1.f/l1, 1.f/l2, 1.f/l3};
#pragma unroll
  for (int i = 0; i < 4; i++) {
    int tok = qt*64 + wid*16 + lg*4 + i;
    if (tok < SEQ) {
      __bf16* dst = o + ((size_t)(b*SEQ + tok))*DMODEL + hh*DHEAD + lr;
#pragma unroll
      for (int db = 0; db < 8; db++) dst[db*16] = (__bf16)(Oacc[db][i] * inv[i]);
    }
  }
}

// ---------------------------------------------------------------- MoE dispatch (ballot scan, 1024 threads)
__global__ __launch_bounds__(1024) void moe_dispatch(const int* __restrict__ idx, int* __restrict__ slot,
                             int* __restrict__ rowmap, int* __restrict__ cnt) {
  int e = blockIdx.x, tid = threadIdx.x;
  int lane = tid & 63, wid = tid >> 6;    // 16 waves
  __shared__ int wsum[16];
  int base = 0;
  for (int c0 = 0; c0 < TKF; c0 += 1024) {
    int f = c0 + tid;
    int match = (f < TKF && idx[f] == e) ? 1 : 0;
    unsigned long long bal = __ballot(match);
    if (lane == 0) wsum[wid] = __popcll(bal);
    __syncthreads();
    int prefix = 0, total = 0;
#pragma unroll
    for (int w2 = 0; w2 < 16; w2++) {
      int v = wsum[w2];
      if (w2 < wid) prefix += v;
      total += v;
    }
    if (match) {
      int pos = base + prefix + __popcll(bal & ((1ull << lane) - 1ull));
      if (pos < CAPACITY) { slot[f] = pos; rowmap[e*CAPACITY + pos] = f; }
      else slot[f] = -1;
    }
    base += total;
    __syncthreads();
  }
  if (tid == 0) cnt[e] = (base < CAPACITY) ? base : CAPACITY;
}

// ---------------------------------------------------------------- MoE combine (yb bf16, fp32 accumulate)
__global__ void moe_sum(const __bf16* __restrict__ y, const int* __restrict__ slot,
                        float* __restrict__ h) {
  int t = blockIdx.x, d4 = threadIdx.x;
  float4 acc = ((float4*)(h + (size_t)t*DMODEL))[d4];
#pragma unroll
  for (int kk = 0; kk < TOPK; kk++) {
    int f = t*TOPK + kk;
    if (slot[f] >= 0) {
      bf16x4 yv = *(const bf16x4*)(y + (size_t)f*DMODEL + d4*4);
      acc.x += (float)yv[0]; acc.y += (float)yv[1];
      acc.z += (float)yv[2]; acc.w += (float)yv[3];
    }
  }
  ((float4*)(h + (size_t)t*DMODEL))[d4] = acc;
}

// ---------------------------------------------------------------- final output
__global__ void final_copy(const float* __restrict__ h, float* __restrict__ out) {
  int b = blockIdx.x, tid = threadIdx.x;
  float4 v = ((const float4*)(h + (size_t)b*SEQ*DMODEL))[tid];
  ((float4*)(out + (size_t)b*DMODEL))[tid] = v;
}

// ---------------------------------------------------------------- host
extern "C" void kernel_launch(void* const* d_in, const int* in_sizes, int n_in,
                              void* d_out, int out_size, void* d_ws, size_t ws_size,
                              hipStream_t stream) {
  (void)in_sizes; (void)n_in; (void)out_size; (void)ws_size;
  const float* x         = (const float*)d_in[0];
  const float* conv_w1   = (const float*)d_in[1];
  const float* conv_w2   = (const float*)d_in[2];
  const float* conv_w3   = (const float*)d_in[3];
  const float* bn1_g     = (const float*)d_in[4];
  const float* bn1_b     = (const float*)d_in[5];
  const float* bn2_g     = (const float*)d_in[6];
  const float* bn2_b     = (const float*)d_in[7];
  const float* bn3_g     = (const float*)d_in[8];
  const float* bn3_b     = (const float*)d_in[9];
  const float* proj_w    = (const float*)d_in[10];
  const float* proj_b    = (const float*)d_in[11];
  const float* cls_token = (const float*)d_in[12];
  const float* mask_tok  = (const float*)d_in[13];
  const float* ln1_g     = (const float*)d_in[14];
  const float* ln1_b     = (const float*)d_in[15];
  const float* ln2_g     = (const float*)d_in[16];
  const float* ln2_b     = (const float*)d_in[17];
  const float* wq        = (const float*)d_in[18];
  const float* wk        = (const float*)d_in[19];
  const float* wv        = (const float*)d_in[20];
  const float* wo        = (const float*)d_in[21];
  const float* bq        = (const float*)d_in[22];
  const float* bk        = (const float*)d_in[23];
  const float* bv        = (const float*)d_in[24];
  const float* bo        = (const float*)d_in[25];
  const float* wg        = (const float*)d_in[26];
  const float* bg        = (const float*)d_in[27];
  const float* we1       = (const float*)d_in[28];
  const float* be1       = (const float*)d_in[29];
  const float* we2       = (const float*)d_in[30];
  const float* be2       = (const float*)d_in[31];
  float* out = (float*)d_out;

  char* base = (char*)d_ws;
  const size_t TDB = (size_t)NTOK * DMODEL * 4;         // 16.8 MB
  float*  h    = (float*)(base);                        // 1 TDB
  __bf16* yb   = (__bf16*)(base + 2*TDB);               // 2 TDB (TKF*1024 bf16)
  __bf16* xbf  = (__bf16*)(base + 6*TDB);               // 0.5 TDB
  __bf16* ao   = (__bf16*)(base + 6*TDB + TDB/2);       // 0.5 TDB
  __bf16* qkvb = (__bf16*)(base + 7*TDB);               // 1.5 TDB (NTOK x 3072 bf16)
  __bf16* hid  = (__bf16*)(base + 8*TDB + TDB/2);       // 2 TDB (TKF*1024 bf16)
  char* misc   = base + 11*TDB;
  float* feat  = (float*)misc;                          // NBINTOT*64
  float* gate  = feat + (size_t)NBINTOT*64;
  int* idx     = (int*)(gate + TKF);
  int* slot    = idx + TKF;
  int* rowmap  = slot + TKF;
  int* cnt     = rowmap + NEXP*CAPACITY;
  int* msk     = cnt + 32;
  char* wtb    = base + 12*TDB;                          // weight area
  const size_t MB1 = (size_t)1024*1024;                  // elems per matrix
  __bf16* wqkv = (__bf16*)wtb;                           // [L][3][1024][1024] packed
  __bf16* wto  = wqkv + 12*MB1;                          // 4 mats
  __bf16* wte1 = wto + 4*MB1;                            // 120 mats
  __bf16* wte2 = wte1 + 120*MB1;                         // 120 mats

  // ---- weight convert+transpose to bf16 [n][k]; QKV packed per layer
  transpose_w<<<dim3(256, 4),   256, 0, stream>>>(wq,  wqkv,           3*MB1);
  transpose_w<<<dim3(256, 4),   256, 0, stream>>>(wk,  wqkv + MB1,     3*MB1);
  transpose_w<<<dim3(256, 4),   256, 0, stream>>>(wv,  wqkv + 2*MB1,   3*MB1);
  transpose_w<<<dim3(256, 4),   256, 0, stream>>>(wo,  wto,            MB1);
  transpose_w<<<dim3(256, 120), 256, 0, stream>>>(we1, wte1,           MB1);
  transpose_w<<<dim3(256, 120), 256, 0, stream>>>(we2, wte2,           MB1);

  conv_frontend<<<NBINTOT, 64, 0, stream>>>(x, conv_w1, conv_w2, conv_w3,
      bn1_g, bn1_b, bn2_g, bn2_b, bn3_g, bn3_b, feat, msk);
  embed_kernel<<<dim3(SEQ, BATCH), 256, 0, stream>>>(feat, msk, proj_w, proj_b,
      cls_token, mask_tok, h);

  int gqkv = RTILES * 24;                // 792  (1-D, XCD-chunked)
  int gwo  = RTILES * 8;                 // 264
  int gmoe = NEXP * 72;                  // 2160
  int gattn = 9 * BATCH * NHEAD;         // 576

  for (int l = 0; l < NLAYER; l++) {
    __bf16* wqkv_l = wqkv + (size_t)l*3*MB1;
    __bf16* wto_l  = wto  + (size_t)l*MB1;
    __bf16* wte1_l = wte1 + (size_t)l*NEXP*MB1;
    __bf16* wte2_l = wte2 + (size_t)l*NEXP*MB1;

    ln_kernel<<<NTOK, 256, 0, stream>>>(h, xbf, ln1_g + (size_t)l*DMODEL, ln1_b + (size_t)l*DMODEL);
    gemm_bf16<0><<<gqkv, 512, 0, stream>>>(xbf, wqkv_l,
        bq + (size_t)l*DMODEL, bk + (size_t)l*DMODEL, bv + (size_t)l*DMODEL,
        qkvb, NTOK, nullptr, nullptr, nullptr);
    attn_mfma<<<gattn, 256, 0, stream>>>(qkvb, ao);
    gemm_bf16<1><<<gwo, 512, 0, stream>>>(ao, wto_l,
        bo + (size_t)l*DMODEL, nullptr, nullptr, h, NTOK, nullptr, nullptr, nullptr);
    ln_gate<<<NTOK, 256, 0, stream>>>(h, xbf, ln2_g + (size_t)l*DMODEL, ln2_b + (size_t)l*DMODEL,
        wg + (size_t)l*DMODEL*NEXP, bg + (size_t)l*NEXP, idx, gate);
    moe_dispatch<<<NEXP, 1024, 0, stream>>>(idx, slot, rowmap, cnt);
    gemm_bf16<2><<<gmoe, 512, 0, stream>>>(xbf, wte1_l,
        be1 + (size_t)l*NEXP*1024, nullptr, nullptr, hid, 0, rowmap, cnt, nullptr);
    gemm_bf16<3><<<gmoe, 512, 0, stream>>>(hid, wte2_l,
        be2 + (size_t)l*NEXP*1024, nullptr, nullptr, yb, 0, rowmap, cnt, gate);
    moe_sum<<<NTOK, 256, 0, stream>>>(yb, slot, h);
  }
  final_copy<<<BATCH, 256, 0, stream>>>(h, out);
}